// Round 1
// baseline (60915.564 us; speedup 1.0000x reference)
//
#include <hip/hip_runtime.h>

#define TT   512
#define NBOX 30
#define HDIM 512
#define M1 (TT*31)     // 15872
#define N1 HDIM        // 512
#define K1 4096
#define M2 (TT*NBOX)   // 15360
#define N2 (3*HDIM)    // 1536
#define K2 (2*HDIM)    // 1024
#define NWG 256

// dynamic LDS layout (floats):
//   Hs  [30][516]          15480   staged h-matrix (padded stride: bank-safe)
//   Wp  [12][516]           6192   P-phase weights: 6 Whh0 cols + 6 Wih1 cols
//   Wq  region              6976   role-dependent (Whh1 cols | W1T rows+hc | coord state)
#define DYN_FLOATS (15480 + 6192 + 6976)
#define DYN_BYTES  (DYN_FLOATS * 4)

__device__ __forceinline__ float4 ld4(const float* p) { return *(const float4*)p; }
__device__ __forceinline__ float dot4(float4 a, float4 b) { return a.x*b.x + a.y*b.y + a.z*b.z + a.w*b.w; }
__device__ __forceinline__ float sigf(float x) { return 1.f / (1.f + __expf(-x)); }
__device__ __forceinline__ float thf(float x)  { return 1.f - 2.f / (1.f + __expf(2.f*x)); }

// ---------------------------------------------------------------------------
// GEMM 1: xv = relu(flow @ W_phi + b_phi)   (unchanged — known correct)
// ---------------------------------------------------------------------------
__global__ __launch_bounds__(256) void gemm_phi(const float* __restrict__ A,
                                                const float* __restrict__ B,
                                                const float* __restrict__ bias,
                                                float* __restrict__ C) {
    __shared__ float As[16][68];
    __shared__ float Bs[16][68];
    const int tid = threadIdx.x;
    const int m0 = blockIdx.x * 64;
    const int n0 = blockIdx.y * 64;
    const int am = tid >> 2, ak = (tid & 3) << 2;
    const int bk = tid >> 4, bn = (tid & 15) << 2;
    const int ty = tid >> 4, tx = tid & 15;
    float acc[4][4] = {};
    for (int k0 = 0; k0 < K1; k0 += 16) {
        const float4 av = *(const float4*)&A[(size_t)(m0 + am) * K1 + k0 + ak];
        const float4 bv = *(const float4*)&B[(size_t)(k0 + bk) * N1 + n0 + bn];
        __syncthreads();
        As[ak + 0][am] = av.x; As[ak + 1][am] = av.y; As[ak + 2][am] = av.z; As[ak + 3][am] = av.w;
        *(float4*)&Bs[bk][bn] = bv;
        __syncthreads();
#pragma unroll
        for (int kk = 0; kk < 16; ++kk) {
            const float4 a = *(const float4*)&As[kk][ty << 2];
            const float4 b = *(const float4*)&Bs[kk][tx << 2];
            const float ar[4] = {a.x, a.y, a.z, a.w};
            const float br[4] = {b.x, b.y, b.z, b.w};
#pragma unroll
            for (int i = 0; i < 4; ++i)
#pragma unroll
                for (int j = 0; j < 4; ++j) acc[i][j] = fmaf(ar[i], br[j], acc[i][j]);
        }
    }
    const float4 bsv = *(const float4*)&bias[n0 + (tx << 2)];
    const float bb[4] = {bsv.x, bsv.y, bsv.z, bsv.w};
#pragma unroll
    for (int i = 0; i < 4; ++i) {
        const int m = m0 + (ty << 2) + i;
        float4 o;
        o.x = fmaxf(acc[i][0] + bb[0], 0.f);
        o.y = fmaxf(acc[i][1] + bb[1], 0.f);
        o.z = fmaxf(acc[i][2] + bb[2], 0.f);
        o.w = fmaxf(acc[i][3] + bb[3], 0.f);
        *(float4*)&C[(size_t)m * N1 + n0 + (tx << 2)] = o;
    }
}

// ---------------------------------------------------------------------------
// GEMM 2: gi0 = x_t @ Wih0^T + bih0  (unchanged)
// ---------------------------------------------------------------------------
__global__ __launch_bounds__(256) void gemm_gi0(const float* __restrict__ xv,
                                                const float* __restrict__ Wih0,
                                                const float* __restrict__ bih0,
                                                float* __restrict__ C) {
    __shared__ float As[16][68];
    __shared__ float Bs[16][68];
    const int tid = threadIdx.x;
    const int m0 = blockIdx.x * 64;
    const int n0 = blockIdx.y * 64;
    const int am = tid >> 2, ak = (tid & 3) << 2;
    const int bn_ = tid >> 2, bkq = (tid & 3) << 2;
    const int ty = tid >> 4, tx = tid & 15;
    const int r = m0 + am;
    const int t = r / 30;
    const int j = r - t * 30;
    const float* rowTrk = xv + ((size_t)(t * 31 + 1 + j) << 9);
    const float* rowImg = xv + ((size_t)(t * 31) << 9);
    float acc[4][4] = {};
    for (int k0 = 0; k0 < K2; k0 += 16) {
        const int kg = k0 + ak;
        const float4 av = (kg < 512) ? *(const float4*)&rowTrk[kg]
                                     : *(const float4*)&rowImg[kg - 512];
        const float4 wv = *(const float4*)&Wih0[(size_t)(n0 + bn_) * K2 + k0 + bkq];
        __syncthreads();
        As[ak + 0][am] = av.x; As[ak + 1][am] = av.y; As[ak + 2][am] = av.z; As[ak + 3][am] = av.w;
        Bs[bkq + 0][bn_] = wv.x; Bs[bkq + 1][bn_] = wv.y; Bs[bkq + 2][bn_] = wv.z; Bs[bkq + 3][bn_] = wv.w;
        __syncthreads();
#pragma unroll
        for (int kk = 0; kk < 16; ++kk) {
            const float4 a = *(const float4*)&As[kk][ty << 2];
            const float4 b = *(const float4*)&Bs[kk][tx << 2];
            const float ar[4] = {a.x, a.y, a.z, a.w};
            const float br[4] = {b.x, b.y, b.z, b.w};
#pragma unroll
            for (int i = 0; i < 4; ++i)
#pragma unroll
                for (int jq = 0; jq < 4; ++jq) acc[i][jq] = fmaf(ar[i], br[jq], acc[i][jq]);
        }
    }
    const float4 bsv = *(const float4*)&bih0[n0 + (tx << 2)];
    const float bb[4] = {bsv.x, bsv.y, bsv.z, bsv.w};
#pragma unroll
    for (int i = 0; i < 4; ++i) {
        const int m = m0 + (ty << 2) + i;
        float4 o;
        o.x = acc[i][0] + bb[0];
        o.y = acc[i][1] + bb[1];
        o.z = acc[i][2] + bb[2];
        o.w = acc[i][3] + bb[3];
        *(float4*)&C[(size_t)m * N2 + n0 + (tx << 2)] = o;
    }
}

// ---------------------------------------------------------------------------
// gic = cor @ Wihc^T + bihc (unchanged)
// ---------------------------------------------------------------------------
__global__ __launch_bounds__(256) void gic_kernel(const int* __restrict__ y,
                                                  const float* __restrict__ Wihc,
                                                  const float* __restrict__ bihc,
                                                  float* __restrict__ gic) {
    const int idx = blockIdx.x * 256 + threadIdx.x;
    if (idx >= M2 * 96) return;
    const int g = idx % 96;
    const int tj = idx / 96;
    const int* yb = y + (size_t)tj * 6;
    const float c0 = (float)yb[1] * (1.f / 1080.f);
    const float c1 = (float)yb[2] * (1.f / 720.f);
    const float c2 = (float)yb[3] * (1.f / 1080.f);
    const float c3 = (float)yb[4] * (1.f / 720.f);
    gic[idx] = bihc[g] + c0 * Wihc[g * 4 + 0] + c1 * Wihc[g * 4 + 1]
                       + c2 * Wihc[g * 4 + 2] + c3 * Wihc[g * 4 + 3];
}

// W1T[u][c] = W1[c][u]  (one-time)
__global__ void transpose_w1(const float* __restrict__ W1, float* __restrict__ W1T) {
    const int idx = blockIdx.x * 256 + threadIdx.x;
    if (idx >= 544 * 256) return;
    const int c = idx % 544, u = idx / 544;
    W1T[idx] = W1[c * 256 + u];
}

__global__ void init_k(unsigned* bar) {
    for (int i = threadIdx.x; i < 1088; i += 256) bar[i] = 0u;
}

// ---------------------------------------------------------------------------
// Two-level grid barrier: 16 groups x 16 WGs. Counters/flags on separate
// 128B lines; monotonic epochs (no reset). <=16 pollers per line.
//   bar[g*32]      : group arrival counter (g<16)
//   bar[512]       : root counter
//   bar[544+g*32]  : group release flag
// ---------------------------------------------------------------------------
__device__ __forceinline__ void gbar(unsigned* bar, unsigned ep, int w) {
    __syncthreads();
    if (threadIdx.x == 0) {
        __threadfence();
        const int g = w >> 4;
        unsigned* gcnt  = bar + g * 32;
        unsigned* gflag = bar + 544 + g * 32;
        const unsigned tgt = ep * 16u;
        unsigned prev = __hip_atomic_fetch_add(gcnt, 1u, __ATOMIC_ACQ_REL, __HIP_MEMORY_SCOPE_AGENT);
        if (prev + 1u == tgt) {
            unsigned prevr = __hip_atomic_fetch_add(bar + 512, 1u, __ATOMIC_ACQ_REL, __HIP_MEMORY_SCOPE_AGENT);
            if (prevr + 1u == tgt) {
                // last WG of the whole grid: release all groups
                for (int i = 0; i < 16; ++i)
                    __hip_atomic_store(bar + 544 + i * 32, ep, __ATOMIC_RELAXED, __HIP_MEMORY_SCOPE_AGENT);
            } else {
                while (__hip_atomic_load(gflag, __ATOMIC_RELAXED, __HIP_MEMORY_SCOPE_AGENT) < ep)
                    __builtin_amdgcn_s_sleep(8);
            }
        } else {
            while (__hip_atomic_load(gflag, __ATOMIC_RELAXED, __HIP_MEMORY_SCOPE_AGENT) < ep)
                __builtin_amdgcn_s_sleep(8);
        }
        __threadfence();
    }
    __syncthreads();
}

// masked softmax over 30 tracks, wave-parallel (call with full wave0: tid<64)
__device__ __forceinline__ void softmax30_wave(const float* raw, const int* yt, float* outp) {
    const int lane = threadIdx.x;
    float sj = 0.f; int pres = 0;
    float mv = -1e30f;
    if (lane < NBOX) {
        sj = raw[lane];
        pres = (yt[lane * 6] != 0);
        if (pres) mv = sj;
    }
    for (int off = 32; off; off >>= 1) mv = fmaxf(mv, __shfl_xor(mv, off));
    float ev = (lane < NBOX && pres) ? __expf(sj - mv) : 0.f;
    float sum = ev;
    for (int off = 32; off; off >>= 1) sum += __shfl_xor(sum, off);
    const float inv = 1.f / fmaxf(sum, 1e-9f);
    if (lane < NBOX) outp[lane] = ev * inv;
}

struct PArgs {
    const float *gi0, *gic;
    const float *Whh0, *Wih1, *Whh1, *Whhc;
    const float *bhh0, *bih1, *bhh1, *bhhc;
    const float *W1T, *b1, *W2, *b2, *wa, *wac;
    const int *y;
    float *Z0, *Z1, *h0, *h1, *hc, *s0raw, *s1raw, *partials, *out;
    unsigned *bar;
};

// ---------------------------------------------------------------------------
// Persistent scan kernel. Per step: P(t) then Q(t), tree barrier after each.
// All hot GEMV operands live in LDS: per-WG weight slices preloaded once
// (fixed for all 512 steps), h-matrix bulk-staged per phase.
// ---------------------------------------------------------------------------
__global__ __launch_bounds__(256, 1) void persist(PArgs A) {
    extern __shared__ float smem[];
    float* Hs = smem;                       // [30][516]
    float* Wp = smem + 15480;               // [12][516]
    float* Wq = smem + 15480 + 6192;        // role region (6976 floats)
    __shared__ float gi_s[NBOX][6];
    __shared__ float sA[NBOX];
    __shared__ float red[256];

    const int w = blockIdx.x;
    const int tid = threadIdx.x;
    unsigned ep = 0;
    float lossSum = 0.f;

    const int w2 = 2 * w;
    const int G2[6] = {w2, 512 + w2, 1024 + w2, w2 + 1, 513 + w2, 1025 + w2};

    // ---- one-time weight preload into LDS (stride 516/548: bank-safe) ----
    {
        const int w6 = 6 * w;
#pragma unroll
        for (int i = 0; i < 6; ++i) {
            const int fid = tid + 256 * i;          // 0..1535
            const int slot = fid >> 7;              // 0..11
            const int k4 = (fid & 127) << 2;        // 0..508
            const float* src = (slot < 6) ? (A.Whh0 + (size_t)(w6 + slot) * 512 + k4)
                                          : (A.Wih1 + (size_t)G2[slot - 6] * 512 + k4);
            *(float4*)&Wp[slot * 516 + k4] = ld4(src);
        }
        if (w < 192) {
#pragma unroll
            for (int i = 0; i < 4; ++i) {
                const int fid = tid + 256 * i;      // 0..1023
                const int slot = fid >> 7, k4 = (fid & 127) << 2;
                *(float4*)&Wq[slot * 516 + k4] = ld4(A.Whh1 + (size_t)(8 * w + slot) * 512 + k4);
            }
        } else if (w < 224) {
            const int b = w - 192;
            for (int fid = tid; fid < 1088; fid += 256) {
                const int u = fid / 136, c4 = (fid - u * 136) << 2;
                *(float4*)&Wq[u * 548 + c4] = ld4(A.W1T + (size_t)(8 * b + u) * 544 + c4);
            }
        } else if (w == NWG - 1) {
            // Whhc -> LDS, zero coord state (chc/cZc/cscr/csca)
            for (int fid = tid; fid < 768; fid += 256)
                *(float4*)&Wq[3904 + (fid << 2)] = ld4(A.Whhc + (fid << 2));
            for (int i = tid; i < 3904; i += 256) Wq[i] = 0.f;
        }
    }

    // ---- per-thread loop-invariant constants (hoisted biases etc.) ----
    const int cjX = tid >> 1, ccX = w2 + (tid & 1);          // h1-combine ids (tid<60)
    const int idxY = w * 60 + tid;                            // h0-combine / INIT ids (tid<60)
    const int cjY = idxY >> 9, ccY = idxY & 511;
    float b1r = 0.f, b1z = 0.f, b1n = 0.f, b0r = 0.f, b0z = 0.f, b0n = 0.f;
    if (tid < 60) {
        b1r = A.bhh1[ccX]; b1z = A.bhh1[512 + ccX]; b1n = A.bhh1[1024 + ccX];
        b0r = A.bhh0[ccY]; b0z = A.bhh0[512 + ccY]; b0n = A.bhh0[1024 + ccY];
    }
    float biA = 0.f, biB = 0.f;
    if (tid < 240 && (tid & 7) >= 3 && (tid & 7) < 6) {
        const int g = ((tid & 7) - 3) * 2;
        biA = A.bih1[G2[g]]; biB = A.bih1[G2[g + 1]];
    }
    float waL = 0.f, waH = 0.f;
    if (w >= 224 && w < 254) { waL = A.wa[tid]; waH = A.wa[tid + 256]; }
    float clb = 0.f, c20 = 0.f, c21 = 0.f;
    if (w >= 192 && w < 224 && tid < 240) {
        const int ug = (w - 192) * 8 + (tid & 7);
        clb = A.b1[ug]; c20 = A.W2[2 * ug]; c21 = A.W2[2 * ug + 1];
    }

    // ---- INIT: h0_n(0) (zero prev state -> s=0 path) ----
    if (tid < 60) {
        const float* gp = A.gi0 + cjY * 1536;
        const float r = sigf(gp[ccY] + b0r);
        const float z = sigf(gp[512 + ccY] + b0z);
        const float n = thf(gp[1024 + ccY] + r * b0n);
        A.h0[idxY] = (1.f - z) * n;
    }
    gbar(A.bar, ++ep, w);

    for (int t = 0; t < TT; ++t) {
        const int parC = t & 1, parP = parC ^ 1;
        // ================= P(t) =================
        {
            // softmaxes on wave 0 (lanes 0..29 active, full wave participates in shuffles)
            if (tid < 64) {
                if (t == 0) { if (tid < NBOX) sA[tid] = 0.f; }
                else softmax30_wave(A.s1raw, A.y + (size_t)(t - 1) * 180, sA);
                if (w == NWG - 1) {
                    float* cscr = Wq + 3840;
                    float* csca = Wq + 3872;
                    if (t == 0) { if (tid < NBOX) csca[tid] = 0.f; }
                    else softmax30_wave(cscr, A.y + (size_t)(t - 1) * 180, csca);
                }
            }
            // stage h0_n(t) -> Hs (bulk: 15 float4 per thread, one latency exposure)
            const float* h0g = A.h0 + parC * 15360;
#pragma unroll
            for (int i = 0; i < 15; ++i) {
                const int e = (tid + 256 * i) << 2;
                *(float4*)&Hs[(e >> 9) * 516 + (e & 511)] = ld4(h0g + e);
            }
            // prefetch h1-combine inputs (cross-WG, global)
            float z1r = 0.f, z1z = 0.f, z1n = 0.f, h1p = 0.f;
            if (tid < 60) {
                z1r = A.Z1[cjX * 1536 + ccX];
                z1z = A.Z1[cjX * 1536 + 512 + ccX];
                z1n = A.Z1[cjX * 1536 + 1024 + ccX];
                h1p = A.h1[parP * 15360 + cjX * 512 + ccX];
            }
            __syncthreads();
            // GEMV from LDS: 6 Whh0 cols -> Z0 (global), 6 Wih1 cols -> gi_s
            if (tid < 240 && (tid & 7) < 6) {
                const int j = tid >> 3, q = tid & 7;
                const float* hrow = &Hs[j * 516];
                const int sa = (q < 3) ? (2 * q) : (6 + (q - 3) * 2);
                const float* wA = &Wp[sa * 516];
                const float* wB = &Wp[(sa + 1) * 516];
                float a0 = 0.f, a1 = 0.f;
#pragma unroll 4
                for (int k = 0; k < 512; k += 4) {
                    const float4 h4 = ld4(hrow + k);
                    a0 += dot4(h4, ld4(wA + k));
                    a1 += dot4(h4, ld4(wB + k));
                }
                if (q < 3) {
                    const int colA = 6 * w + 2 * q;
                    A.Z0[j * 1536 + colA]     = a0;
                    A.Z0[j * 1536 + colA + 1] = a1;
                } else {
                    const int g = (q - 3) * 2;
                    gi_s[j][g]     = a0 + biA;
                    gi_s[j][g + 1] = a1 + biB;
                }
            }
            __syncthreads();
            // fused h1-combine: h1_n(t)
            if (tid < 60) {
                const float s = sA[cjX];
                const int ci = tid & 1;
                const float r = sigf(gi_s[cjX][ci * 3 + 0] + s * z1r + b1r);
                const float z = sigf(gi_s[cjX][ci * 3 + 1] + s * z1z + b1z);
                const float n = thf (gi_s[cjX][ci * 3 + 2] + r * (s * z1n + b1n));
                A.h1[parC * 15360 + cjX * 512 + ccX] = (1.f - z) * n + z * (s * h1p);
            }
            // s0 raw attention dots (from LDS Hs)
            if (w >= 224 && w < 254) {
                const int jd = w - 224;
                const float* hrow = &Hs[jd * 516];
                red[tid] = thf(hrow[tid]) * waL + thf(hrow[tid + 256]) * waH;
                __syncthreads();
                for (int sft = 128; sft > 0; sft >>= 1) {
                    if (tid < sft) red[tid] += red[tid + sft];
                    __syncthreads();
                }
                if (tid == 0) A.s0raw[jd] = red[0];
            }
            // coord-GRU chain (WG255, persistent LDS overlay in Wq)
            if (w == NWG - 1) {
                float* chc  = Wq;
                float* cZc  = Wq + 960;
                float* cscr = Wq + 3840;
                float* csca = Wq + 3872;
                float* Whs  = Wq + 3904;
                for (int idx = tid; idx < 960; idx += 256) {
                    const int j = idx >> 5, c = idx & 31;
                    const float s = csca[j];
                    const float* gp = A.gic + (size_t)t * 2880 + j * 96;
                    const float r = sigf(gp[c]      + s * cZc[j * 96 + c]      + A.bhhc[c]);
                    const float z = sigf(gp[32 + c] + s * cZc[j * 96 + 32 + c] + A.bhhc[32 + c]);
                    const float n = thf (gp[64 + c] + r * (s * cZc[j * 96 + 64 + c] + A.bhhc[64 + c]));
                    const float hn = (1.f - z) * n + z * (s * chc[idx]);
                    chc[idx] = hn;
                    A.hc[idx] = hn;
                }
                __syncthreads();
                for (int idx = tid; idx < 2880; idx += 256) {
                    const int j = idx / 96, g = idx - j * 96;
                    const float* wr = Whs + g * 32;
                    const float* hr = chc + j * 32;
                    float a = 0.f;
#pragma unroll
                    for (int c2 = 0; c2 < 32; c2 += 4) a += dot4(ld4(hr + c2), ld4(wr + c2));
                    cZc[idx] = a;
                }
                if (tid < 240) {
                    const int j = tid >> 3, seg = tid & 7;
                    float p = 0.f;
                    for (int c2 = seg * 4; c2 < seg * 4 + 4; ++c2) p += thf(chc[j * 32 + c2]) * A.wac[c2];
                    p += __shfl_down(p, 4, 8);
                    p += __shfl_down(p, 2, 8);
                    p += __shfl_down(p, 1, 8);
                    if (seg == 0) cscr[j] = p;
                }
            }
        }
        gbar(A.bar, ++ep, w);
        // ================= Q(t) =================
        {
            const float* h1g = A.h1 + parC * 15360;
            if (tid < 64) softmax30_wave(A.s0raw, A.y + (size_t)t * 180, sA);
            // stage h1_n(t) -> Hs
#pragma unroll
            for (int i = 0; i < 15; ++i) {
                const int e = (tid + 256 * i) << 2;
                *(float4*)&Hs[(e >> 9) * 516 + (e & 511)] = ld4(h1g + e);
            }
            // stage hc for classifier WGs (stride 36: bank-safe)
            float* hcs = Wq + 4384;
            if (w >= 192 && w < 224 && tid < 240) {
                const int e = tid << 2;
                *(float4*)&hcs[(e >> 5) * 36 + (e & 31)] = ld4(A.hc + e);
            }
            // prefetch h0-combine(t+1) inputs
            float g_r = 0.f, g_z = 0.f, g_n = 0.f, z0r = 0.f, z0z = 0.f, z0n = 0.f, h0p = 0.f;
            if (tid < 60 && t < TT - 1) {
                const float* gp = A.gi0 + (size_t)(t + 1) * 46080 + cjY * 1536;
                g_r = gp[ccY]; g_z = gp[512 + ccY]; g_n = gp[1024 + ccY];
                z0r = A.Z0[cjY * 1536 + ccY];
                z0z = A.Z0[cjY * 1536 + 512 + ccY];
                z0n = A.Z0[cjY * 1536 + 1024 + ccY];
                h0p = A.h0[parC * 15360 + idxY];
            }
            __syncthreads();
            if (w < 192) {
                // Z1 GEMV: 8 cols from LDS
                if (tid < 240 && (tid & 7) < 4) {
                    const int j = tid >> 3, q = tid & 7;
                    const float* hrow = &Hs[j * 516];
                    const float* wA = &Wq[(2 * q) * 516];
                    const float* wB = &Wq[(2 * q + 1) * 516];
                    float a0 = 0.f, a1 = 0.f;
#pragma unroll 4
                    for (int k = 0; k < 512; k += 4) {
                        const float4 h4 = ld4(hrow + k);
                        a0 += dot4(h4, ld4(wA + k));
                        a1 += dot4(h4, ld4(wB + k));
                    }
                    const int colA = 8 * w + 2 * q;
                    A.Z1[j * 1536 + colA]     = a0;
                    A.Z1[j * 1536 + colA + 1] = a1;
                }
            } else if (w < 224) {
                // classifier partials: 8 hidden units x 30 tracks (all LDS operands)
                if (tid < 240) {
                    const int j = tid >> 3, u = tid & 7;
                    const float* w1r = &Wq[u * 548];
                    const float* hrow = &Hs[j * 516];
                    float acc = clb;
#pragma unroll 4
                    for (int c2 = 0; c2 < 512; c2 += 4) acc += dot4(ld4(hrow + c2), ld4(w1r + c2));
                    const float* hcr = &hcs[j * 36];
#pragma unroll
                    for (int c2 = 0; c2 < 32; c2 += 4) acc += dot4(ld4(hcr + c2), ld4(w1r + 512 + c2));
                    const float uu = fmaxf(acc, 0.f);
                    float p0 = uu * c20, p1 = uu * c21;
                    p0 += __shfl_down(p0, 4, 8); p0 += __shfl_down(p0, 2, 8); p0 += __shfl_down(p0, 1, 8);
                    p1 += __shfl_down(p1, 4, 8); p1 += __shfl_down(p1, 2, 8); p1 += __shfl_down(p1, 1, 8);
                    if (u == 0) {
                        float* pp = A.partials + (t & 1) * 1920 + (w - 192) * 60 + j * 2;
                        pp[0] = p0; pp[1] = p1;
                    }
                }
            } else if (w < 254) {
                // s1 raw attention dots (from LDS Hs)
                const int jd = w - 224;
                const float* hrow = &Hs[jd * 516];
                red[tid] = thf(hrow[tid]) * waL + thf(hrow[tid + 256]) * waH;
                __syncthreads();
                for (int sft = 128; sft > 0; sft >>= 1) {
                    if (tid < sft) red[tid] += red[tid + sft];
                    __syncthreads();
                }
                if (tid == 0) A.s1raw[jd] = red[0];
            } else if (w == 254 && t > 0) {
                // finalize classifier for t-1
                const int tt = t - 1, par = tt & 1;
                if (tid < 30) {
                    float o0 = A.b2[0], o1 = A.b2[1];
                    const float* pp = A.partials + par * 1920;
                    for (int b2i = 0; b2i < 32; ++b2i) {
                        o0 += pp[b2i * 60 + tid * 2];
                        o1 += pp[b2i * 60 + tid * 2 + 1];
                    }
                    const int* yb = A.y + (size_t)tt * 180 + tid * 6;
                    const float pm = (yb[0] != 0) ? 1.f : 0.f;
                    const float m = fmaxf(o0, o1);
                    const float lse = m + __logf(__expf(o0 - m) + __expf(o1 - m));
                    const float lt = (yb[5] == 0) ? o0 : o1;
                    red[tid] = pm * (lse - lt);
                    A.out[1 + (size_t)tt * 60 + tid * 2]     = o0 * pm;
                    A.out[1 + (size_t)tt * 60 + tid * 2 + 1] = o1 * pm;
                }
                __syncthreads();
                if (tid == 0) { float s = 0.f; for (int j = 0; j < NBOX; ++j) s += red[j]; lossSum += s; }
            }
            __syncthreads();
            // h0-combine(t+1)
            if (tid < 60 && t < TT - 1) {
                const float s = sA[cjY];
                const float r = sigf(g_r + s * z0r + b0r);
                const float z = sigf(g_z + s * z0z + b0z);
                const float n = thf (g_n + r * (s * z0n + b0n));
                A.h0[parP * 15360 + cjY * 512 + ccY] = (1.f - z) * n + z * (s * h0p);
            }
        }
        gbar(A.bar, ++ep, w);
    }
    // ---- epilogue: finalize t=511, write total loss
    if (w == 254) {
        const int tt = TT - 1, par = tt & 1;
        if (tid < 30) {
            float o0 = A.b2[0], o1 = A.b2[1];
            const float* pp = A.partials + par * 1920;
            for (int b2i = 0; b2i < 32; ++b2i) {
                o0 += pp[b2i * 60 + tid * 2];
                o1 += pp[b2i * 60 + tid * 2 + 1];
            }
            const int* yb = A.y + (size_t)tt * 180 + tid * 6;
            const float pm = (yb[0] != 0) ? 1.f : 0.f;
            const float m = fmaxf(o0, o1);
            const float lse = m + __logf(__expf(o0 - m) + __expf(o1 - m));
            const float lt = (yb[5] == 0) ? o0 : o1;
            red[tid] = pm * (lse - lt);
            A.out[1 + (size_t)tt * 60 + tid * 2]     = o0 * pm;
            A.out[1 + (size_t)tt * 60 + tid * 2 + 1] = o1 * pm;
        }
        __syncthreads();
        if (tid == 0) {
            float s = 0.f;
            for (int j = 0; j < NBOX; ++j) s += red[j];
            A.out[0] = lossSum + s;
        }
    }
}

// ---------------------------------------------------------------------------
extern "C" void kernel_launch(void* const* d_in, const int* in_sizes, int n_in,
                              void* d_out, int out_size, void* d_ws, size_t ws_size,
                              hipStream_t stream) {
    (void)in_sizes; (void)n_in; (void)out_size; (void)ws_size;
    const int*   y     = (const int*)d_in[1];
    const float* flow  = (const float*)d_in[2];
    const float* W_phi = (const float*)d_in[3];
    const float* b_phi = (const float*)d_in[4];
    const float* Wih0  = (const float*)d_in[5];
    const float* Whh0  = (const float*)d_in[6];
    const float* bih0  = (const float*)d_in[7];
    const float* bhh0  = (const float*)d_in[8];
    const float* Wih1  = (const float*)d_in[9];
    const float* Whh1  = (const float*)d_in[10];
    const float* bih1  = (const float*)d_in[11];
    const float* bhh1  = (const float*)d_in[12];
    const float* Whhc  = (const float*)d_in[14];
    const float* bihc  = (const float*)d_in[15];
    const float* bhhc  = (const float*)d_in[16];
    const float* Wihc  = (const float*)d_in[13];
    const float* W1    = (const float*)d_in[17];
    const float* b1    = (const float*)d_in[18];
    const float* W2    = (const float*)d_in[19];
    const float* b2    = (const float*)d_in[20];
    const float* wa    = (const float*)d_in[21];
    const float* wac   = (const float*)d_in[22];
    float* out = (float*)d_out;

    float* ws = (float*)d_ws;
    float* xv   = ws;  ws += (size_t)M1 * N1;
    float* gi0  = ws;  ws += (size_t)M2 * N2;
    float* gic  = ws;  ws += (size_t)M2 * 96;
    float* W1T  = ws;  ws += 544 * 256;
    float* Z0   = ws;  ws += NBOX * 1536;
    float* Z1   = ws;  ws += NBOX * 1536;
    float* h0   = ws;  ws += 2 * NBOX * 512;
    float* h1   = ws;  ws += 2 * NBOX * 512;
    float* hc   = ws;  ws += NBOX * 32;
    float* s0raw = ws; ws += 32;
    float* s1raw = ws; ws += 32;
    float* partials = ws; ws += 2 * 32 * NBOX * 2;
    unsigned* barmem = (unsigned*)ws; ws += 1088;

    (void)hipFuncSetAttribute((const void*)persist,
                              hipFuncAttributeMaxDynamicSharedMemorySize, DYN_BYTES);

    hipLaunchKernelGGL(init_k, dim3(1), dim3(256), 0, stream, barmem);
    hipLaunchKernelGGL(gemm_phi, dim3(M1 / 64, N1 / 64), dim3(256), 0, stream, flow, W_phi, b_phi, xv);
    hipLaunchKernelGGL(gemm_gi0, dim3(M2 / 64, N2 / 64), dim3(256), 0, stream, xv, Wih0, bih0, gi0);
    hipLaunchKernelGGL(gic_kernel, dim3((M2 * 96 + 255) / 256), dim3(256), 0, stream, y, Wihc, bihc, gic);
    hipLaunchKernelGGL(transpose_w1, dim3((544 * 256 + 255) / 256), dim3(256), 0, stream, W1, W1T);

    PArgs A;
    A.gi0 = gi0; A.gic = gic;
    A.Whh0 = Whh0; A.Wih1 = Wih1; A.Whh1 = Whh1; A.Whhc = Whhc;
    A.bhh0 = bhh0; A.bih1 = bih1; A.bhh1 = bhh1; A.bhhc = bhhc;
    A.W1T = W1T; A.b1 = b1; A.W2 = W2; A.b2 = b2; A.wa = wa; A.wac = wac;
    A.y = y;
    A.Z0 = Z0; A.Z1 = Z1; A.h0 = h0; A.h1 = h1; A.hc = hc;
    A.s0raw = s0raw; A.s1raw = s1raw; A.partials = partials; A.out = out;
    A.bar = barmem;
    hipLaunchKernelGGL(persist, dim3(NWG), dim3(256), DYN_BYTES, stream, A);
}

// Round 2
// 53364.502 us; speedup vs baseline: 1.1415x; 1.1415x over previous
//
#include <hip/hip_runtime.h>

#define TT   512
#define NBOX 30
#define HDIM 512
#define M1 (TT*31)     // 15872
#define N1 HDIM        // 512
#define K1 4096
#define M2 (TT*NBOX)   // 15360
#define N2 (3*HDIM)    // 1536
#define K2 (2*HDIM)    // 1024
#define NWG 256

// dynamic LDS layout (floats):
//   Hs  [30][516]          15480   staged h-matrix (padded stride: bank-safe)
//   Wp  [12][516]           6192   P-phase weights: 6 Whh0 cols + 6 Wih1 cols
//   Wq  region              6976   role-dependent (Whh1 cols | W1T rows+hc | coord state)
#define DYN_FLOATS (15480 + 6192 + 6976)
#define DYN_BYTES  (DYN_FLOATS * 4)

__device__ __forceinline__ float4 ld4(const float* p) { return *(const float4*)p; }
__device__ __forceinline__ float dot4(float4 a, float4 b) { return a.x*b.x + a.y*b.y + a.z*b.z + a.w*b.w; }
__device__ __forceinline__ float sigf(float x) { return 1.f / (1.f + __expf(-x)); }
__device__ __forceinline__ float thf(float x)  { return 1.f - 2.f / (1.f + __expf(2.f*x)); }

// --- coherent (L2-bypassing, LLC-visible) accessors: NO fences anywhere ----
__device__ __forceinline__ float ldg_c(const float* p) {
    return __hip_atomic_load((float*)p, __ATOMIC_RELAXED, __HIP_MEMORY_SCOPE_AGENT);
}
__device__ __forceinline__ void stg_c(float* p, float v) {
    __hip_atomic_store(p, v, __ATOMIC_RELAXED, __HIP_MEMORY_SCOPE_AGENT);
}
__device__ __forceinline__ float2 ldg_c2(const float* p) {
    unsigned long long u = __hip_atomic_load((unsigned long long*)p, __ATOMIC_RELAXED, __HIP_MEMORY_SCOPE_AGENT);
    float2 r;
    r.x = __uint_as_float((unsigned)u);
    r.y = __uint_as_float((unsigned)(u >> 32));
    return r;
}
__device__ __forceinline__ void stg_c2(float* p, float a, float b) {
    unsigned long long u = ((unsigned long long)__float_as_uint(b) << 32) | (unsigned long long)__float_as_uint(a);
    __hip_atomic_store((unsigned long long*)p, u, __ATOMIC_RELAXED, __HIP_MEMORY_SCOPE_AGENT);
}

// ---------------------------------------------------------------------------
// GEMM 1: xv = relu(flow @ W_phi + b_phi)   (unchanged — known correct)
// ---------------------------------------------------------------------------
__global__ __launch_bounds__(256) void gemm_phi(const float* __restrict__ A,
                                                const float* __restrict__ B,
                                                const float* __restrict__ bias,
                                                float* __restrict__ C) {
    __shared__ float As[16][68];
    __shared__ float Bs[16][68];
    const int tid = threadIdx.x;
    const int m0 = blockIdx.x * 64;
    const int n0 = blockIdx.y * 64;
    const int am = tid >> 2, ak = (tid & 3) << 2;
    const int bk = tid >> 4, bn = (tid & 15) << 2;
    const int ty = tid >> 4, tx = tid & 15;
    float acc[4][4] = {};
    for (int k0 = 0; k0 < K1; k0 += 16) {
        const float4 av = *(const float4*)&A[(size_t)(m0 + am) * K1 + k0 + ak];
        const float4 bv = *(const float4*)&B[(size_t)(k0 + bk) * N1 + n0 + bn];
        __syncthreads();
        As[ak + 0][am] = av.x; As[ak + 1][am] = av.y; As[ak + 2][am] = av.z; As[ak + 3][am] = av.w;
        *(float4*)&Bs[bk][bn] = bv;
        __syncthreads();
#pragma unroll
        for (int kk = 0; kk < 16; ++kk) {
            const float4 a = *(const float4*)&As[kk][ty << 2];
            const float4 b = *(const float4*)&Bs[kk][tx << 2];
            const float ar[4] = {a.x, a.y, a.z, a.w};
            const float br[4] = {b.x, b.y, b.z, b.w};
#pragma unroll
            for (int i = 0; i < 4; ++i)
#pragma unroll
                for (int j = 0; j < 4; ++j) acc[i][j] = fmaf(ar[i], br[j], acc[i][j]);
        }
    }
    const float4 bsv = *(const float4*)&bias[n0 + (tx << 2)];
    const float bb[4] = {bsv.x, bsv.y, bsv.z, bsv.w};
#pragma unroll
    for (int i = 0; i < 4; ++i) {
        const int m = m0 + (ty << 2) + i;
        float4 o;
        o.x = fmaxf(acc[i][0] + bb[0], 0.f);
        o.y = fmaxf(acc[i][1] + bb[1], 0.f);
        o.z = fmaxf(acc[i][2] + bb[2], 0.f);
        o.w = fmaxf(acc[i][3] + bb[3], 0.f);
        *(float4*)&C[(size_t)m * N1 + n0 + (tx << 2)] = o;
    }
}

// ---------------------------------------------------------------------------
// GEMM 2: gi0 = x_t @ Wih0^T + bih0  (unchanged)
// ---------------------------------------------------------------------------
__global__ __launch_bounds__(256) void gemm_gi0(const float* __restrict__ xv,
                                                const float* __restrict__ Wih0,
                                                const float* __restrict__ bih0,
                                                float* __restrict__ C) {
    __shared__ float As[16][68];
    __shared__ float Bs[16][68];
    const int tid = threadIdx.x;
    const int m0 = blockIdx.x * 64;
    const int n0 = blockIdx.y * 64;
    const int am = tid >> 2, ak = (tid & 3) << 2;
    const int bn_ = tid >> 2, bkq = (tid & 3) << 2;
    const int ty = tid >> 4, tx = tid & 15;
    const int r = m0 + am;
    const int t = r / 30;
    const int j = r - t * 30;
    const float* rowTrk = xv + ((size_t)(t * 31 + 1 + j) << 9);
    const float* rowImg = xv + ((size_t)(t * 31) << 9);
    float acc[4][4] = {};
    for (int k0 = 0; k0 < K2; k0 += 16) {
        const int kg = k0 + ak;
        const float4 av = (kg < 512) ? *(const float4*)&rowTrk[kg]
                                     : *(const float4*)&rowImg[kg - 512];
        const float4 wv = *(const float4*)&Wih0[(size_t)(n0 + bn_) * K2 + k0 + bkq];
        __syncthreads();
        As[ak + 0][am] = av.x; As[ak + 1][am] = av.y; As[ak + 2][am] = av.z; As[ak + 3][am] = av.w;
        Bs[bkq + 0][bn_] = wv.x; Bs[bkq + 1][bn_] = wv.y; Bs[bkq + 2][bn_] = wv.z; Bs[bkq + 3][bn_] = wv.w;
        __syncthreads();
#pragma unroll
        for (int kk = 0; kk < 16; ++kk) {
            const float4 a = *(const float4*)&As[kk][ty << 2];
            const float4 b = *(const float4*)&Bs[kk][tx << 2];
            const float ar[4] = {a.x, a.y, a.z, a.w};
            const float br[4] = {b.x, b.y, b.z, b.w};
#pragma unroll
            for (int i = 0; i < 4; ++i)
#pragma unroll
                for (int jq = 0; jq < 4; ++jq) acc[i][jq] = fmaf(ar[i], br[jq], acc[i][jq]);
        }
    }
    const float4 bsv = *(const float4*)&bih0[n0 + (tx << 2)];
    const float bb[4] = {bsv.x, bsv.y, bsv.z, bsv.w};
#pragma unroll
    for (int i = 0; i < 4; ++i) {
        const int m = m0 + (ty << 2) + i;
        float4 o;
        o.x = acc[i][0] + bb[0];
        o.y = acc[i][1] + bb[1];
        o.z = acc[i][2] + bb[2];
        o.w = acc[i][3] + bb[3];
        *(float4*)&C[(size_t)m * N2 + n0 + (tx << 2)] = o;
    }
}

// ---------------------------------------------------------------------------
// gic = cor @ Wihc^T + bihc (unchanged)
// ---------------------------------------------------------------------------
__global__ __launch_bounds__(256) void gic_kernel(const int* __restrict__ y,
                                                  const float* __restrict__ Wihc,
                                                  const float* __restrict__ bihc,
                                                  float* __restrict__ gic) {
    const int idx = blockIdx.x * 256 + threadIdx.x;
    if (idx >= M2 * 96) return;
    const int g = idx % 96;
    const int tj = idx / 96;
    const int* yb = y + (size_t)tj * 6;
    const float c0 = (float)yb[1] * (1.f / 1080.f);
    const float c1 = (float)yb[2] * (1.f / 720.f);
    const float c2 = (float)yb[3] * (1.f / 1080.f);
    const float c3 = (float)yb[4] * (1.f / 720.f);
    gic[idx] = bihc[g] + c0 * Wihc[g * 4 + 0] + c1 * Wihc[g * 4 + 1]
                       + c2 * Wihc[g * 4 + 2] + c3 * Wihc[g * 4 + 3];
}

// W1T[u][c] = W1[c][u]  (one-time)
__global__ void transpose_w1(const float* __restrict__ W1, float* __restrict__ W1T) {
    const int idx = blockIdx.x * 256 + threadIdx.x;
    if (idx >= 544 * 256) return;
    const int c = idx % 544, u = idx / 544;
    W1T[idx] = W1[c * 256 + u];
}

__global__ void init_k(unsigned* bar) {
    for (int i = threadIdx.x; i < 1088; i += 256) bar[i] = 0u;
}

// ---------------------------------------------------------------------------
// Two-level grid barrier, FENCE-FREE. All cross-WG data moves via relaxed
// agent-scope (sc1, L2-bypassing) loads/stores; __syncthreads drains each
// wave's vmcnt before s_barrier, so by the time tid0 issues the arrival RMW
// every wave's write-through stores are at the LLC. No buffer_wbl2/buffer_inv.
//   bar[g*32]      : group arrival counter (g<16)
//   bar[512]       : root counter
//   bar[544+g*32]  : group release flag
// ---------------------------------------------------------------------------
__device__ __forceinline__ void gbar(unsigned* bar, unsigned ep, int w) {
    __syncthreads();
    if (threadIdx.x == 0) {
        asm volatile("" ::: "memory");
        const int g = w >> 4;
        unsigned* gcnt  = bar + g * 32;
        unsigned* gflag = bar + 544 + g * 32;
        const unsigned tgt = ep * 16u;
        unsigned prev = __hip_atomic_fetch_add(gcnt, 1u, __ATOMIC_RELAXED, __HIP_MEMORY_SCOPE_AGENT);
        if (prev + 1u == tgt) {
            unsigned prevr = __hip_atomic_fetch_add(bar + 512, 1u, __ATOMIC_RELAXED, __HIP_MEMORY_SCOPE_AGENT);
            if (prevr + 1u == tgt) {
                for (int i = 0; i < 16; ++i)
                    __hip_atomic_store(bar + 544 + i * 32, ep, __ATOMIC_RELAXED, __HIP_MEMORY_SCOPE_AGENT);
            } else {
                while (__hip_atomic_load(gflag, __ATOMIC_RELAXED, __HIP_MEMORY_SCOPE_AGENT) < ep)
                    __builtin_amdgcn_s_sleep(2);
            }
        } else {
            while (__hip_atomic_load(gflag, __ATOMIC_RELAXED, __HIP_MEMORY_SCOPE_AGENT) < ep)
                __builtin_amdgcn_s_sleep(2);
        }
        asm volatile("" ::: "memory");
    }
    __syncthreads();
}

// masked softmax over 30 tracks, wave-parallel; sj/pres are per-lane inputs
__device__ __forceinline__ void softmax30_wave(float sj, int pres, float* outp) {
    const int lane = threadIdx.x;
    float mv = pres ? sj : -1e30f;
    for (int off = 32; off; off >>= 1) mv = fmaxf(mv, __shfl_xor(mv, off));
    float ev = pres ? __expf(sj - mv) : 0.f;
    float sum = ev;
    for (int off = 32; off; off >>= 1) sum += __shfl_xor(sum, off);
    const float inv = 1.f / fmaxf(sum, 1e-9f);
    if (lane < NBOX) outp[lane] = ev * inv;
}

struct PArgs {
    const float *gi0, *gic;
    const float *Whh0, *Wih1, *Whh1, *Whhc;
    const float *bhh0, *bih1, *bhh1, *bhhc;
    const float *W1T, *b1, *W2, *b2, *wa, *wac;
    const int *y;
    float *Z0, *Z1, *h0, *h1, *hc, *s0raw, *s1raw, *partials, *out;
    unsigned *bar;
};

// ---------------------------------------------------------------------------
// Persistent scan kernel. Per step: P(t) then Q(t), fence-free barrier after
// each. Rotating state via agent-scope bypass accessors (ldg_c/stg_c);
// read-only data (weights/gi0/y/biases) stays L2-cached for all 512 steps.
// ---------------------------------------------------------------------------
__global__ __launch_bounds__(256, 1) void persist(PArgs A) {
    extern __shared__ float smem[];
    float* Hs = smem;                       // [30][516]
    float* Wp = smem + 15480;               // [12][516]
    float* Wq = smem + 15480 + 6192;        // role region (6976 floats)
    __shared__ float gi_s[NBOX][6];
    __shared__ float sA[NBOX];
    __shared__ float red[256];

    const int w = blockIdx.x;
    const int tid = threadIdx.x;
    unsigned ep = 0;
    float lossSum = 0.f;

    const int w2 = 2 * w;
    const int G2[6] = {w2, 512 + w2, 1024 + w2, w2 + 1, 513 + w2, 1025 + w2};

    // ---- one-time weight preload into LDS (stride 516/548: bank-safe) ----
    {
        const int w6 = 6 * w;
#pragma unroll
        for (int i = 0; i < 6; ++i) {
            const int fid = tid + 256 * i;          // 0..1535
            const int slot = fid >> 7;              // 0..11
            const int k4 = (fid & 127) << 2;        // 0..508
            const float* src = (slot < 6) ? (A.Whh0 + (size_t)(w6 + slot) * 512 + k4)
                                          : (A.Wih1 + (size_t)G2[slot - 6] * 512 + k4);
            *(float4*)&Wp[slot * 516 + k4] = ld4(src);
        }
        if (w < 192) {
#pragma unroll
            for (int i = 0; i < 4; ++i) {
                const int fid = tid + 256 * i;      // 0..1023
                const int slot = fid >> 7, k4 = (fid & 127) << 2;
                *(float4*)&Wq[slot * 516 + k4] = ld4(A.Whh1 + (size_t)(8 * w + slot) * 512 + k4);
            }
        } else if (w < 224) {
            const int b = w - 192;
            for (int fid = tid; fid < 1088; fid += 256) {
                const int u = fid / 136, c4 = (fid - u * 136) << 2;
                *(float4*)&Wq[u * 548 + c4] = ld4(A.W1T + (size_t)(8 * b + u) * 544 + c4);
            }
        } else if (w == NWG - 1) {
            // Whhc -> LDS, zero coord state (chc/cZc/cscr/csca)
            for (int fid = tid; fid < 768; fid += 256)
                *(float4*)&Wq[3904 + (fid << 2)] = ld4(A.Whhc + (fid << 2));
            for (int i = tid; i < 3904; i += 256) Wq[i] = 0.f;
        }
    }

    // ---- per-thread loop-invariant constants (hoisted biases etc.) ----
    const int cjX = tid >> 1, ccX = w2 + (tid & 1);          // h1-combine ids (tid<60)
    const int idxY = w * 60 + tid;                            // h0-combine / INIT ids (tid<60)
    const int cjY = idxY >> 9, ccY = idxY & 511;
    float b1r = 0.f, b1z = 0.f, b1n = 0.f, b0r = 0.f, b0z = 0.f, b0n = 0.f;
    if (tid < 60) {
        b1r = A.bhh1[ccX]; b1z = A.bhh1[512 + ccX]; b1n = A.bhh1[1024 + ccX];
        b0r = A.bhh0[ccY]; b0z = A.bhh0[512 + ccY]; b0n = A.bhh0[1024 + ccY];
    }
    float biA = 0.f, biB = 0.f;
    if (tid < 240 && (tid & 7) >= 3 && (tid & 7) < 6) {
        const int g = ((tid & 7) - 3) * 2;
        biA = A.bih1[G2[g]]; biB = A.bih1[G2[g + 1]];
    }
    float waL = 0.f, waH = 0.f;
    if (w >= 224 && w < 254) { waL = A.wa[tid]; waH = A.wa[tid + 256]; }
    float clb = 0.f, c20 = 0.f, c21 = 0.f;
    if (w >= 192 && w < 224 && tid < 240) {
        const int ug = (w - 192) * 8 + (tid & 7);
        clb = A.b1[ug]; c20 = A.W2[2 * ug]; c21 = A.W2[2 * ug + 1];
    }

    // ---- INIT: h0_n(0) (zero prev state -> s=0 path) ----
    if (tid < 60) {
        const float* gp = A.gi0 + cjY * 1536;
        const float r = sigf(gp[ccY] + b0r);
        const float z = sigf(gp[512 + ccY] + b0z);
        const float n = thf(gp[1024 + ccY] + r * b0n);
        stg_c(A.h0 + idxY, (1.f - z) * n);
    }
    gbar(A.bar, ++ep, w);

    for (int t = 0; t < TT; ++t) {
        const int parC = t & 1, parP = parC ^ 1;
        // ================= P(t) =================
        {
            // softmaxes on wave 0 (lanes 0..29 active, full wave in shuffles)
            if (tid < 64) {
                if (t == 0) { if (tid < NBOX) sA[tid] = 0.f; }
                else {
                    const int* yt = A.y + (size_t)(t - 1) * 180;
                    float sj = 0.f; int pres = 0;
                    if (tid < NBOX) { sj = ldg_c(A.s1raw + tid); pres = (yt[tid * 6] != 0); }
                    softmax30_wave(sj, pres, sA);
                }
                if (w == NWG - 1) {
                    float* cscr = Wq + 3840;
                    float* csca = Wq + 3872;
                    if (t == 0) { if (tid < NBOX) csca[tid] = 0.f; }
                    else {
                        const int* yt = A.y + (size_t)(t - 1) * 180;
                        float sj = 0.f; int pres = 0;
                        if (tid < NBOX) { sj = cscr[tid]; pres = (yt[tid * 6] != 0); }
                        softmax30_wave(sj, pres, csca);
                    }
                }
            }
            // stage h0_n(t) -> Hs (bypass loads, one latency exposure)
            const float* h0g = A.h0 + parC * 15360;
#pragma unroll
            for (int i = 0; i < 30; ++i) {
                const int fi = tid + 256 * i;       // float2 index 0..7679
                const int e = fi << 1;              // float index (even)
                const float2 v = ldg_c2(h0g + e);
                *(float2*)&Hs[(e >> 9) * 516 + (e & 511)] = v;
            }
            // prefetch h1-combine inputs (cross-WG)
            float z1r = 0.f, z1z = 0.f, z1n = 0.f, h1p = 0.f;
            if (tid < 60) {
                z1r = ldg_c(A.Z1 + cjX * 1536 + ccX);
                z1z = ldg_c(A.Z1 + cjX * 1536 + 512 + ccX);
                z1n = ldg_c(A.Z1 + cjX * 1536 + 1024 + ccX);
                h1p = ldg_c(A.h1 + parP * 15360 + cjX * 512 + ccX);
            }
            __syncthreads();
            // GEMV from LDS: 6 Whh0 cols -> Z0 (bypass store), 6 Wih1 cols -> gi_s
            if (tid < 240 && (tid & 7) < 6) {
                const int j = tid >> 3, q = tid & 7;
                const float* hrow = &Hs[j * 516];
                const int sa = (q < 3) ? (2 * q) : (6 + (q - 3) * 2);
                const float* wA = &Wp[sa * 516];
                const float* wB = &Wp[(sa + 1) * 516];
                float a0 = 0.f, a1 = 0.f;
#pragma unroll 4
                for (int k = 0; k < 512; k += 4) {
                    const float4 h4 = ld4(hrow + k);
                    a0 += dot4(h4, ld4(wA + k));
                    a1 += dot4(h4, ld4(wB + k));
                }
                if (q < 3) {
                    const int colA = 6 * w + 2 * q;
                    stg_c2(A.Z0 + j * 1536 + colA, a0, a1);
                } else {
                    const int g = (q - 3) * 2;
                    gi_s[j][g]     = a0 + biA;
                    gi_s[j][g + 1] = a1 + biB;
                }
            }
            __syncthreads();
            // fused h1-combine: h1_n(t)
            if (tid < 60) {
                const float s = sA[cjX];
                const int ci = tid & 1;
                const float r = sigf(gi_s[cjX][ci * 3 + 0] + s * z1r + b1r);
                const float z = sigf(gi_s[cjX][ci * 3 + 1] + s * z1z + b1z);
                const float n = thf (gi_s[cjX][ci * 3 + 2] + r * (s * z1n + b1n));
                stg_c(A.h1 + parC * 15360 + cjX * 512 + ccX, (1.f - z) * n + z * (s * h1p));
            }
            // s0 raw attention dots (from LDS Hs)
            if (w >= 224 && w < 254) {
                const int jd = w - 224;
                const float* hrow = &Hs[jd * 516];
                red[tid] = thf(hrow[tid]) * waL + thf(hrow[tid + 256]) * waH;
                __syncthreads();
                for (int sft = 128; sft > 0; sft >>= 1) {
                    if (tid < sft) red[tid] += red[tid + sft];
                    __syncthreads();
                }
                if (tid == 0) stg_c(A.s0raw + jd, red[0]);
            }
            // coord-GRU chain (WG255, persistent LDS overlay in Wq)
            if (w == NWG - 1) {
                float* chc  = Wq;
                float* cZc  = Wq + 960;
                float* cscr = Wq + 3840;
                float* csca = Wq + 3872;
                float* Whs  = Wq + 3904;
                for (int idx = tid; idx < 960; idx += 256) {
                    const int j = idx >> 5, c = idx & 31;
                    const float s = csca[j];
                    const float* gp = A.gic + (size_t)t * 2880 + j * 96;
                    const float r = sigf(gp[c]      + s * cZc[j * 96 + c]      + A.bhhc[c]);
                    const float z = sigf(gp[32 + c] + s * cZc[j * 96 + 32 + c] + A.bhhc[32 + c]);
                    const float n = thf (gp[64 + c] + r * (s * cZc[j * 96 + 64 + c] + A.bhhc[64 + c]));
                    const float hn = (1.f - z) * n + z * (s * chc[idx]);
                    chc[idx] = hn;
                    stg_c(A.hc + idx, hn);
                }
                __syncthreads();
                for (int idx = tid; idx < 2880; idx += 256) {
                    const int j = idx / 96, g = idx - j * 96;
                    const float* wr = Whs + g * 32;
                    const float* hr = chc + j * 32;
                    float a = 0.f;
#pragma unroll
                    for (int c2 = 0; c2 < 32; c2 += 4) a += dot4(ld4(hr + c2), ld4(wr + c2));
                    cZc[idx] = a;
                }
                if (tid < 240) {
                    const int j = tid >> 3, seg = tid & 7;
                    float p = 0.f;
                    for (int c2 = seg * 4; c2 < seg * 4 + 4; ++c2) p += thf(chc[j * 32 + c2]) * A.wac[c2];
                    p += __shfl_down(p, 4, 8);
                    p += __shfl_down(p, 2, 8);
                    p += __shfl_down(p, 1, 8);
                    if (seg == 0) cscr[j] = p;
                }
            }
        }
        gbar(A.bar, ++ep, w);
        // ================= Q(t) =================
        {
            const float* h1g = A.h1 + parC * 15360;
            if (tid < 64) {
                const int* yt = A.y + (size_t)t * 180;
                float sj = 0.f; int pres = 0;
                if (tid < NBOX) { sj = ldg_c(A.s0raw + tid); pres = (yt[tid * 6] != 0); }
                softmax30_wave(sj, pres, sA);
            }
            // stage h1_n(t) -> Hs (bypass loads)
#pragma unroll
            for (int i = 0; i < 30; ++i) {
                const int fi = tid + 256 * i;
                const int e = fi << 1;
                const float2 v = ldg_c2(h1g + e);
                *(float2*)&Hs[(e >> 9) * 516 + (e & 511)] = v;
            }
            // stage hc for classifier WGs (stride 36: bank-safe)
            float* hcs = Wq + 4384;
            if (w >= 192 && w < 224) {
                for (int fi = tid; fi < 480; fi += 256) {
                    const int e = fi << 1;
                    const float2 v = ldg_c2(A.hc + e);
                    *(float2*)&hcs[(e >> 5) * 36 + (e & 31)] = v;
                }
            }
            // prefetch h0-combine(t+1) inputs
            float g_r = 0.f, g_z = 0.f, g_n = 0.f, z0r = 0.f, z0z = 0.f, z0n = 0.f, h0p = 0.f;
            if (tid < 60 && t < TT - 1) {
                const float* gp = A.gi0 + (size_t)(t + 1) * 46080 + cjY * 1536;
                g_r = gp[ccY]; g_z = gp[512 + ccY]; g_n = gp[1024 + ccY];
                z0r = ldg_c(A.Z0 + cjY * 1536 + ccY);
                z0z = ldg_c(A.Z0 + cjY * 1536 + 512 + ccY);
                z0n = ldg_c(A.Z0 + cjY * 1536 + 1024 + ccY);
                h0p = ldg_c(A.h0 + parC * 15360 + idxY);
            }
            __syncthreads();
            if (w < 192) {
                // Z1 GEMV: 8 cols from LDS
                if (tid < 240 && (tid & 7) < 4) {
                    const int j = tid >> 3, q = tid & 7;
                    const float* hrow = &Hs[j * 516];
                    const float* wA = &Wq[(2 * q) * 516];
                    const float* wB = &Wq[(2 * q + 1) * 516];
                    float a0 = 0.f, a1 = 0.f;
#pragma unroll 4
                    for (int k = 0; k < 512; k += 4) {
                        const float4 h4 = ld4(hrow + k);
                        a0 += dot4(h4, ld4(wA + k));
                        a1 += dot4(h4, ld4(wB + k));
                    }
                    const int colA = 8 * w + 2 * q;
                    stg_c2(A.Z1 + j * 1536 + colA, a0, a1);
                }
            } else if (w < 224) {
                // classifier partials: 8 hidden units x 30 tracks (LDS operands)
                if (tid < 240) {
                    const int j = tid >> 3, u = tid & 7;
                    const float* w1r = &Wq[u * 548];
                    const float* hrow = &Hs[j * 516];
                    float acc = clb;
#pragma unroll 4
                    for (int c2 = 0; c2 < 512; c2 += 4) acc += dot4(ld4(hrow + c2), ld4(w1r + c2));
                    const float* hcr = &hcs[j * 36];
#pragma unroll
                    for (int c2 = 0; c2 < 32; c2 += 4) acc += dot4(ld4(hcr + c2), ld4(w1r + 512 + c2));
                    const float uu = fmaxf(acc, 0.f);
                    float p0 = uu * c20, p1 = uu * c21;
                    p0 += __shfl_down(p0, 4, 8); p0 += __shfl_down(p0, 2, 8); p0 += __shfl_down(p0, 1, 8);
                    p1 += __shfl_down(p1, 4, 8); p1 += __shfl_down(p1, 2, 8); p1 += __shfl_down(p1, 1, 8);
                    if (u == 0) {
                        float* pp = A.partials + (t & 1) * 1920 + (w - 192) * 60 + j * 2;
                        stg_c2(pp, p0, p1);
                    }
                }
            } else if (w < 254) {
                // s1 raw attention dots (from LDS Hs)
                const int jd = w - 224;
                const float* hrow = &Hs[jd * 516];
                red[tid] = thf(hrow[tid]) * waL + thf(hrow[tid + 256]) * waH;
                __syncthreads();
                for (int sft = 128; sft > 0; sft >>= 1) {
                    if (tid < sft) red[tid] += red[tid + sft];
                    __syncthreads();
                }
                if (tid == 0) stg_c(A.s1raw + jd, red[0]);
            } else if (w == 254 && t > 0) {
                // finalize classifier for t-1
                const int tt = t - 1, par = tt & 1;
                if (tid < 30) {
                    float o0 = A.b2[0], o1 = A.b2[1];
                    const float* pp = A.partials + par * 1920;
                    for (int b2i = 0; b2i < 32; ++b2i) {
                        const float2 v = ldg_c2(pp + b2i * 60 + tid * 2);
                        o0 += v.x; o1 += v.y;
                    }
                    const int* yb = A.y + (size_t)tt * 180 + tid * 6;
                    const float pm = (yb[0] != 0) ? 1.f : 0.f;
                    const float m = fmaxf(o0, o1);
                    const float lse = m + __logf(__expf(o0 - m) + __expf(o1 - m));
                    const float lt = (yb[5] == 0) ? o0 : o1;
                    red[tid] = pm * (lse - lt);
                    A.out[1 + (size_t)tt * 60 + tid * 2]     = o0 * pm;
                    A.out[1 + (size_t)tt * 60 + tid * 2 + 1] = o1 * pm;
                }
                __syncthreads();
                if (tid == 0) { float s = 0.f; for (int j = 0; j < NBOX; ++j) s += red[j]; lossSum += s; }
            }
            __syncthreads();
            // h0-combine(t+1)
            if (tid < 60 && t < TT - 1) {
                const float s = sA[cjY];
                const float r = sigf(g_r + s * z0r + b0r);
                const float z = sigf(g_z + s * z0z + b0z);
                const float n = thf (g_n + r * (s * z0n + b0n));
                stg_c(A.h0 + parP * 15360 + cjY * 512 + ccY, (1.f - z) * n + z * (s * h0p));
            }
        }
        gbar(A.bar, ++ep, w);
    }
    // ---- epilogue: finalize t=511, write total loss
    if (w == 254) {
        const int tt = TT - 1, par = tt & 1;
        if (tid < 30) {
            float o0 = A.b2[0], o1 = A.b2[1];
            const float* pp = A.partials + par * 1920;
            for (int b2i = 0; b2i < 32; ++b2i) {
                const float2 v = ldg_c2(pp + b2i * 60 + tid * 2);
                o0 += v.x; o1 += v.y;
            }
            const int* yb = A.y + (size_t)tt * 180 + tid * 6;
            const float pm = (yb[0] != 0) ? 1.f : 0.f;
            const float m = fmaxf(o0, o1);
            const float lse = m + __logf(__expf(o0 - m) + __expf(o1 - m));
            const float lt = (yb[5] == 0) ? o0 : o1;
            red[tid] = pm * (lse - lt);
            A.out[1 + (size_t)tt * 60 + tid * 2]     = o0 * pm;
            A.out[1 + (size_t)tt * 60 + tid * 2 + 1] = o1 * pm;
        }
        __syncthreads();
        if (tid == 0) {
            float s = 0.f;
            for (int j = 0; j < NBOX; ++j) s += red[j];
            A.out[0] = lossSum + s;
        }
    }
}

// ---------------------------------------------------------------------------
extern "C" void kernel_launch(void* const* d_in, const int* in_sizes, int n_in,
                              void* d_out, int out_size, void* d_ws, size_t ws_size,
                              hipStream_t stream) {
    (void)in_sizes; (void)n_in; (void)out_size; (void)ws_size;
    const int*   y     = (const int*)d_in[1];
    const float* flow  = (const float*)d_in[2];
    const float* W_phi = (const float*)d_in[3];
    const float* b_phi = (const float*)d_in[4];
    const float* Wih0  = (const float*)d_in[5];
    const float* Whh0  = (const float*)d_in[6];
    const float* bih0  = (const float*)d_in[7];
    const float* bhh0  = (const float*)d_in[8];
    const float* Wih1  = (const float*)d_in[9];
    const float* Whh1  = (const float*)d_in[10];
    const float* bih1  = (const float*)d_in[11];
    const float* bhh1  = (const float*)d_in[12];
    const float* Whhc  = (const float*)d_in[14];
    const float* bihc  = (const float*)d_in[15];
    const float* bhhc  = (const float*)d_in[16];
    const float* Wihc  = (const float*)d_in[13];
    const float* W1    = (const float*)d_in[17];
    const float* b1    = (const float*)d_in[18];
    const float* W2    = (const float*)d_in[19];
    const float* b2    = (const float*)d_in[20];
    const float* wa    = (const float*)d_in[21];
    const float* wac   = (const float*)d_in[22];
    float* out = (float*)d_out;

    float* ws = (float*)d_ws;
    float* xv   = ws;  ws += (size_t)M1 * N1;
    float* gi0  = ws;  ws += (size_t)M2 * N2;
    float* gic  = ws;  ws += (size_t)M2 * 96;
    float* W1T  = ws;  ws += 544 * 256;
    float* Z0   = ws;  ws += NBOX * 1536;
    float* Z1   = ws;  ws += NBOX * 1536;
    float* h0   = ws;  ws += 2 * NBOX * 512;
    float* h1   = ws;  ws += 2 * NBOX * 512;
    float* hc   = ws;  ws += NBOX * 32;
    float* s0raw = ws; ws += 32;
    float* s1raw = ws; ws += 32;
    float* partials = ws; ws += 2 * 32 * NBOX * 2;
    unsigned* barmem = (unsigned*)ws; ws += 1088;

    (void)hipFuncSetAttribute((const void*)persist,
                              hipFuncAttributeMaxDynamicSharedMemorySize, DYN_BYTES);

    hipLaunchKernelGGL(init_k, dim3(1), dim3(256), 0, stream, barmem);
    hipLaunchKernelGGL(gemm_phi, dim3(M1 / 64, N1 / 64), dim3(256), 0, stream, flow, W_phi, b_phi, xv);
    hipLaunchKernelGGL(gemm_gi0, dim3(M2 / 64, N2 / 64), dim3(256), 0, stream, xv, Wih0, bih0, gi0);
    hipLaunchKernelGGL(gic_kernel, dim3((M2 * 96 + 255) / 256), dim3(256), 0, stream, y, Wihc, bihc, gic);
    hipLaunchKernelGGL(transpose_w1, dim3((544 * 256 + 255) / 256), dim3(256), 0, stream, W1, W1T);

    PArgs A;
    A.gi0 = gi0; A.gic = gic;
    A.Whh0 = Whh0; A.Wih1 = Wih1; A.Whh1 = Whh1; A.Whhc = Whhc;
    A.bhh0 = bhh0; A.bih1 = bih1; A.bhh1 = bhh1; A.bhhc = bhhc;
    A.W1T = W1T; A.b1 = b1; A.W2 = W2; A.b2 = b2; A.wa = wa; A.wac = wac;
    A.y = y;
    A.Z0 = Z0; A.Z1 = Z1; A.h0 = h0; A.h1 = h1; A.hc = hc;
    A.s0raw = s0raw; A.s1raw = s1raw; A.partials = partials; A.out = out;
    A.bar = barmem;
    hipLaunchKernelGGL(persist, dim3(NWG), dim3(256), DYN_BYTES, stream, A);
}

// Round 3
// 36803.680 us; speedup vs baseline: 1.6551x; 1.4500x over previous
//
#include <hip/hip_runtime.h>

#define TT   512
#define NBOX 30
#define HDIM 512
#define M1 (TT*31)     // 15872
#define N1 HDIM        // 512
#define K1 4096
#define M2 (TT*NBOX)   // 15360
#define N2 (3*HDIM)    // 1536
#define K2 (2*HDIM)    // 1024
#define NWG 256

// dynamic LDS layout (floats):
//   Hs0  [30][516]   15480  @0      staged h0_n(t)
//   Hs1  [30][516]   15480  @15480  staged h1_n(t-1)
//   Wp   [18][516]    9288  @30960  Whh0/Wih1/Whh1 col-triples (WG255: coord overlay)
//   gi_s [30][6]       180  @40248
//   Z0s  [30][6]       180  @40428
//   Z1s  [30][6]       180  @40608
//   sm0  [32]           32  @40788
//   sm1  [32]           32  @40820
//   redF [72]           72  @40852
#define DYN_FLOATS 40924
#define DYN_BYTES  (DYN_FLOATS * 4)

__device__ __forceinline__ float4 ld4(const float* p) { return *(const float4*)p; }
__device__ __forceinline__ float dot4(float4 a, float4 b) { return a.x*b.x + a.y*b.y + a.z*b.z + a.w*b.w; }
__device__ __forceinline__ float sigf(float x) { return 1.f / (1.f + __expf(-x)); }
__device__ __forceinline__ float thf(float x)  { return 1.f - 2.f / (1.f + __expf(2.f*x)); }

// --- coherent (L2-bypassing, LLC-visible) accessors: no fences anywhere ----
__device__ __forceinline__ float ldg_c(const float* p) {
    return __hip_atomic_load((float*)p, __ATOMIC_RELAXED, __HIP_MEMORY_SCOPE_AGENT);
}
__device__ __forceinline__ void stg_c(float* p, float v) {
    __hip_atomic_store(p, v, __ATOMIC_RELAXED, __HIP_MEMORY_SCOPE_AGENT);
}
__device__ __forceinline__ float2 ldg_c2(const float* p) {
    unsigned long long u = __hip_atomic_load((unsigned long long*)p, __ATOMIC_RELAXED, __HIP_MEMORY_SCOPE_AGENT);
    float2 r;
    r.x = __uint_as_float((unsigned)u);
    r.y = __uint_as_float((unsigned)(u >> 32));
    return r;
}
__device__ __forceinline__ void stg_c2(float* p, float a, float b) {
    unsigned long long u = ((unsigned long long)__float_as_uint(b) << 32) | (unsigned long long)__float_as_uint(a);
    __hip_atomic_store((unsigned long long*)p, u, __ATOMIC_RELAXED, __HIP_MEMORY_SCOPE_AGENT);
}

// ---------------------------------------------------------------------------
// GEMM 1: xv = relu(flow @ W_phi + b_phi)   (unchanged)
// ---------------------------------------------------------------------------
__global__ __launch_bounds__(256) void gemm_phi(const float* __restrict__ A,
                                                const float* __restrict__ B,
                                                const float* __restrict__ bias,
                                                float* __restrict__ C) {
    __shared__ float As[16][68];
    __shared__ float Bs[16][68];
    const int tid = threadIdx.x;
    const int m0 = blockIdx.x * 64;
    const int n0 = blockIdx.y * 64;
    const int am = tid >> 2, ak = (tid & 3) << 2;
    const int bk = tid >> 4, bn = (tid & 15) << 2;
    const int ty = tid >> 4, tx = tid & 15;
    float acc[4][4] = {};
    for (int k0 = 0; k0 < K1; k0 += 16) {
        const float4 av = *(const float4*)&A[(size_t)(m0 + am) * K1 + k0 + ak];
        const float4 bv = *(const float4*)&B[(size_t)(k0 + bk) * N1 + n0 + bn];
        __syncthreads();
        As[ak + 0][am] = av.x; As[ak + 1][am] = av.y; As[ak + 2][am] = av.z; As[ak + 3][am] = av.w;
        *(float4*)&Bs[bk][bn] = bv;
        __syncthreads();
#pragma unroll
        for (int kk = 0; kk < 16; ++kk) {
            const float4 a = *(const float4*)&As[kk][ty << 2];
            const float4 b = *(const float4*)&Bs[kk][tx << 2];
            const float ar[4] = {a.x, a.y, a.z, a.w};
            const float br[4] = {b.x, b.y, b.z, b.w};
#pragma unroll
            for (int i = 0; i < 4; ++i)
#pragma unroll
                for (int j = 0; j < 4; ++j) acc[i][j] = fmaf(ar[i], br[j], acc[i][j]);
        }
    }
    const float4 bsv = *(const float4*)&bias[n0 + (tx << 2)];
    const float bb[4] = {bsv.x, bsv.y, bsv.z, bsv.w};
#pragma unroll
    for (int i = 0; i < 4; ++i) {
        const int m = m0 + (ty << 2) + i;
        float4 o;
        o.x = fmaxf(acc[i][0] + bb[0], 0.f);
        o.y = fmaxf(acc[i][1] + bb[1], 0.f);
        o.z = fmaxf(acc[i][2] + bb[2], 0.f);
        o.w = fmaxf(acc[i][3] + bb[3], 0.f);
        *(float4*)&C[(size_t)m * N1 + n0 + (tx << 2)] = o;
    }
}

// ---------------------------------------------------------------------------
// GEMM 2: gi0 = x_t @ Wih0^T + bih0  (unchanged)
// ---------------------------------------------------------------------------
__global__ __launch_bounds__(256) void gemm_gi0(const float* __restrict__ xv,
                                                const float* __restrict__ Wih0,
                                                const float* __restrict__ bih0,
                                                float* __restrict__ C) {
    __shared__ float As[16][68];
    __shared__ float Bs[16][68];
    const int tid = threadIdx.x;
    const int m0 = blockIdx.x * 64;
    const int n0 = blockIdx.y * 64;
    const int am = tid >> 2, ak = (tid & 3) << 2;
    const int bn_ = tid >> 2, bkq = (tid & 3) << 2;
    const int ty = tid >> 4, tx = tid & 15;
    const int r = m0 + am;
    const int t = r / 30;
    const int j = r - t * 30;
    const float* rowTrk = xv + ((size_t)(t * 31 + 1 + j) << 9);
    const float* rowImg = xv + ((size_t)(t * 31) << 9);
    float acc[4][4] = {};
    for (int k0 = 0; k0 < K2; k0 += 16) {
        const int kg = k0 + ak;
        const float4 av = (kg < 512) ? *(const float4*)&rowTrk[kg]
                                     : *(const float4*)&rowImg[kg - 512];
        const float4 wv = *(const float4*)&Wih0[(size_t)(n0 + bn_) * K2 + k0 + bkq];
        __syncthreads();
        As[ak + 0][am] = av.x; As[ak + 1][am] = av.y; As[ak + 2][am] = av.z; As[ak + 3][am] = av.w;
        Bs[bkq + 0][bn_] = wv.x; Bs[bkq + 1][bn_] = wv.y; Bs[bkq + 2][bn_] = wv.z; Bs[bkq + 3][bn_] = wv.w;
        __syncthreads();
#pragma unroll
        for (int kk = 0; kk < 16; ++kk) {
            const float4 a = *(const float4*)&As[kk][ty << 2];
            const float4 b = *(const float4*)&Bs[kk][tx << 2];
            const float ar[4] = {a.x, a.y, a.z, a.w};
            const float br[4] = {b.x, b.y, b.z, b.w};
#pragma unroll
            for (int i = 0; i < 4; ++i)
#pragma unroll
                for (int jq = 0; jq < 4; ++jq) acc[i][jq] = fmaf(ar[i], br[jq], acc[i][jq]);
        }
    }
    const float4 bsv = *(const float4*)&bih0[n0 + (tx << 2)];
    const float bb[4] = {bsv.x, bsv.y, bsv.z, bsv.w};
#pragma unroll
    for (int i = 0; i < 4; ++i) {
        const int m = m0 + (ty << 2) + i;
        float4 o;
        o.x = acc[i][0] + bb[0];
        o.y = acc[i][1] + bb[1];
        o.z = acc[i][2] + bb[2];
        o.w = acc[i][3] + bb[3];
        *(float4*)&C[(size_t)m * N2 + n0 + (tx << 2)] = o;
    }
}

// ---------------------------------------------------------------------------
// gic = cor @ Wihc^T + bihc (unchanged)
// ---------------------------------------------------------------------------
__global__ __launch_bounds__(256) void gic_kernel(const int* __restrict__ y,
                                                  const float* __restrict__ Wihc,
                                                  const float* __restrict__ bihc,
                                                  float* __restrict__ gic) {
    const int idx = blockIdx.x * 256 + threadIdx.x;
    if (idx >= M2 * 96) return;
    const int g = idx % 96;
    const int tj = idx / 96;
    const int* yb = y + (size_t)tj * 6;
    const float c0 = (float)yb[1] * (1.f / 1080.f);
    const float c1 = (float)yb[2] * (1.f / 720.f);
    const float c2 = (float)yb[3] * (1.f / 1080.f);
    const float c3 = (float)yb[4] * (1.f / 720.f);
    gic[idx] = bihc[g] + c0 * Wihc[g * 4 + 0] + c1 * Wihc[g * 4 + 1]
                       + c2 * Wihc[g * 4 + 2] + c3 * Wihc[g * 4 + 3];
}

// W1T[u][c] = W1[c][u]  (one-time)
__global__ void transpose_w1(const float* __restrict__ W1, float* __restrict__ W1T) {
    const int idx = blockIdx.x * 256 + threadIdx.x;
    if (idx >= 544 * 256) return;
    const int c = idx % 544, u = idx / 544;
    W1T[idx] = W1[c * 256 + u];
}

__global__ void init_k(unsigned* bar) {
    for (int i = threadIdx.x; i < 1088; i += 256) bar[i] = 0u;
}

// ---------------------------------------------------------------------------
// Two-level fence-free grid barrier (16 groups x 16 WGs), monotonic epochs.
// ---------------------------------------------------------------------------
__device__ __forceinline__ void gbar(unsigned* bar, unsigned ep, int w) {
    __syncthreads();
    if (threadIdx.x == 0) {
        asm volatile("" ::: "memory");
        const int g = w >> 4;
        unsigned* gcnt  = bar + g * 32;
        unsigned* gflag = bar + 544 + g * 32;
        const unsigned tgt = ep * 16u;
        unsigned prev = __hip_atomic_fetch_add(gcnt, 1u, __ATOMIC_RELAXED, __HIP_MEMORY_SCOPE_AGENT);
        if (prev + 1u == tgt) {
            unsigned prevr = __hip_atomic_fetch_add(bar + 512, 1u, __ATOMIC_RELAXED, __HIP_MEMORY_SCOPE_AGENT);
            if (prevr + 1u == tgt) {
                for (int i = 0; i < 16; ++i)
                    __hip_atomic_store(bar + 544 + i * 32, ep, __ATOMIC_RELAXED, __HIP_MEMORY_SCOPE_AGENT);
            } else {
                while (__hip_atomic_load(gflag, __ATOMIC_RELAXED, __HIP_MEMORY_SCOPE_AGENT) < ep)
                    __builtin_amdgcn_s_sleep(2);
            }
        } else {
            while (__hip_atomic_load(gflag, __ATOMIC_RELAXED, __HIP_MEMORY_SCOPE_AGENT) < ep)
                __builtin_amdgcn_s_sleep(2);
        }
        asm volatile("" ::: "memory");
    }
    __syncthreads();
}

// masked softmax over 30 tracks; executes on one full wave; lane param explicit
__device__ __forceinline__ void softmax30_lane(int lane, float sj, int pres, float* outp) {
    float mv = pres ? sj : -1e30f;
    for (int off = 32; off; off >>= 1) mv = fmaxf(mv, __shfl_xor(mv, off));
    float ev = pres ? __expf(sj - mv) : 0.f;
    float sum = ev;
    for (int off = 32; off; off >>= 1) sum += __shfl_xor(sum, off);
    const float inv = 1.f / fmaxf(sum, 1e-9f);
    if (lane < NBOX) outp[lane] = ev * inv;
}

__device__ __forceinline__ void coord_gemv_elem(const float* chc, const float* Whhc, int e, float* cz) {
    const int j = e >> 5, c = e & 31;
    const float* hr = chc + j * 32;
#pragma unroll
    for (int m2 = 0; m2 < 3; ++m2) {
        const float* wr = Whhc + (size_t)(c + 32 * m2) * 32;
        float a = 0.f;
#pragma unroll
        for (int c2 = 0; c2 < 32; c2 += 4) a += dot4(ld4(hr + c2), ld4(wr + c2));
        cz[m2] = a;
    }
}

__device__ __forceinline__ void coord_comb_elem(float* chc, const float* gp, const float* bhhc,
                                                const float* csca, float* hcout, int e, const float* cz) {
    const int j = e >> 5, c = e & 31;
    const float s = csca[j];
    const float r = sigf(gp[j*96 + c]      + s*cz[0] + bhhc[c]);
    const float z = sigf(gp[j*96 + 32 + c] + s*cz[1] + bhhc[32+c]);
    const float n = thf (gp[j*96 + 64 + c] + r*(s*cz[2] + bhhc[64+c]));
    const float hn = (1.f - z)*n + z*(s*chc[e]);
    chc[e] = hn;
    stg_c(hcout + e, hn);
}

struct PArgs {
    const float *gi0, *gic;
    const float *Whh0, *Wih1, *Whh1, *Whhc;
    const float *bhh0, *bih1, *bhh1, *bhhc;
    const float *W1T, *b1, *W2, *b2, *wa, *wac;
    const int *y;
    float *h0g, *h1g, *hcg, *partials, *lossbuf, *out;
    unsigned *bar;
};

// ---------------------------------------------------------------------------
// Fused persistent scan: ONE grid barrier per step (515 phases + init + tail).
// WG w owns hidden columns {2w, 2w+1} of Whh0/Wih1/Whh1 (18 gate-cols in LDS).
// Z0(t), gi1(t), Z1(t-1) computed AND consumed inside one phase (LDS-local).
// Scores/softmax computed redundantly per WG. Classifier 1 unit/WG @ t-2,
// finalize on WGs 0-29 @ t-3, coord GRU on WG255 (LDS overlay + reg cZ).
// ---------------------------------------------------------------------------
__global__ __launch_bounds__(256, 1) void persist(PArgs A) {
    extern __shared__ float smem[];
    float* Hs0  = smem;
    float* Hs1  = smem + 15480;
    float* Wp   = smem + 30960;
    float* gi_s = smem + 40248;
    float* Z0s  = smem + 40428;
    float* Z1s  = smem + 40608;
    float* sm0  = smem + 40788;
    float* sm1  = smem + 40820;
    float* redF = smem + 40852;

    const int w = blockIdx.x;
    const int tid = threadIdx.x;
    const bool isCoord = (w == NWG - 1);
    unsigned ep = 0;
    float lossSum = 0.f;

    // ---- one-time preload: weight col-triples into LDS (slot stride 516) ----
    if (!isCoord) {
#pragma unroll
        for (int i = 0; i < 9; ++i) {
            const int fid = tid + 256 * i;            // 0..2303
            const int slot = fid >> 7;                // 0..17
            const int k4 = (fid & 127) << 2;          // 0..508
            const int sl = slot % 6;
            const int col = (sl % 3) * 512 + 2 * w + ((sl >= 3) ? 1 : 0);
            const float* mat = (slot < 6) ? A.Whh0 : (slot < 12) ? A.Wih1 : A.Whh1;
            *(float4*)&Wp[slot * 516 + k4] = ld4(mat + (size_t)col * 512 + k4);
        }
    } else {
        for (int i = tid; i < 1024; i += 256) Wp[i] = 0.f;  // chc(960)+cscr(32)+csca(32)
    }
    if (tid < 180) Z1s[tid] = 0.f;                    // t=0 reads with s=0

    // ---- hoisted per-thread constants ----
    const int cjX = tid >> 1, ciX = tid & 1, cX = 2 * w + ciX;   // combine map (tid<60)
    float b0r=0,b0z=0,b0n=0,b1r=0,b1z=0,b1n=0;
    if (tid < 60) {
        b0r = A.bhh0[cX]; b0z = A.bhh0[512+cX]; b0n = A.bhh0[1024+cX];
        b1r = A.bhh1[cX]; b1z = A.bhh1[512+cX]; b1n = A.bhh1[1024+cX];
    }
    float biA = 0.f, biB = 0.f;
    {
        const int q = tid & 7;
        if (tid < 240 && q >= 3 && q < 6) {
            const int slA = 2 * (q - 3), slB = slA + 1;
            biA = A.bih1[(slA % 3) * 512 + 2 * w + ((slA >= 3) ? 1 : 0)];
            biB = A.bih1[(slB % 3) * 512 + 2 * w + ((slB >= 3) ? 1 : 0)];
        }
    }
    float clb=0,c20=0,c21=0, clb2=0,c202=0,c212=0;
    if (!isCoord) { clb = A.b1[w]; c20 = A.W2[2*w]; c21 = A.W2[2*w+1]; }
    if (w == 254) { clb2 = A.b1[255]; c202 = A.W2[510]; c212 = A.W2[511]; }

    float cz0[3]={0,0,0}, cz1[3]={0,0,0}, cz2[3]={0,0,0}, cz3[3]={0,0,0};

    // ---- INIT: h0_n(0) (zero state -> s=0 path), publish to h0g slot 0 ----
    if (tid < 60) {
        const float* gp = A.gi0 + cjX * 1536;
        const float r = sigf(gp[cX] + b0r);
        const float z = sigf(gp[512 + cX] + b0z);
        const float n = thf(gp[1024 + cX] + r * b0n);
        stg_c(A.h0g + cjX * 512 + cX, (1.f - z) * n);
    }
    gbar(A.bar, ++ep, w);

    for (int t = 0; t < TT + 3; ++t) {
        // ================= S0: stage + gi0 prefetch =================
        if (t <= 511) {
            const float* src = A.h0g + (t & 1) * 15360;
#pragma unroll
            for (int i = 0; i < 30; ++i) {
                const int e = (tid + 256 * i) << 1;
                *(float2*)&Hs0[(e >> 9) * 516 + (e & 511)] = ldg_c2(src + e);
            }
        }
        if (t >= 1 && t <= 512) {
            const float* src = A.h1g + ((t + 2) % 3) * 15360;
#pragma unroll
            for (int i = 0; i < 30; ++i) {
                const int e = (tid + 256 * i) << 1;
                *(float2*)&Hs1[(e >> 9) * 516 + (e & 511)] = ldg_c2(src + e);
            }
        } else if (t == 0) {
#pragma unroll
            for (int i = 0; i < 30; ++i) {
                const int e = (tid + 256 * i) << 1;
                *(float2*)&Hs1[(e >> 9) * 516 + (e & 511)] = make_float2(0.f, 0.f);
            }
        }
        float g_r = 0.f, g_z = 0.f, g_n = 0.f;
        if (tid < 60 && t <= 510) {
            const float* gp = A.gi0 + (size_t)(t + 1) * 46080 + cjX * 1536;
            g_r = gp[cX]; g_z = gp[512 + cX]; g_n = gp[1024 + cX];
        }
        __syncthreads();   // Hs ready

        // ================= S1: redundant attention scores =================
        if (tid < 240 && t <= 511) {
            const int j = tid >> 3, seg = tid & 7;
            const float* wap = A.wa + seg * 64;
            {
                const float* hp = &Hs0[j * 516 + seg * 64];
                float a0 = 0.f;
#pragma unroll 8
                for (int i = 0; i < 64; ++i) a0 += thf(hp[i]) * wap[i];
                a0 += __shfl_down(a0, 4, 8); a0 += __shfl_down(a0, 2, 8); a0 += __shfl_down(a0, 1, 8);
                if (seg == 0) redF[j] = a0;
            }
            if (t >= 1) {
                const float* hp = &Hs1[j * 516 + seg * 64];
                float a1 = 0.f;
#pragma unroll 8
                for (int i = 0; i < 64; ++i) a1 += thf(hp[i]) * wap[i];
                a1 += __shfl_down(a1, 4, 8); a1 += __shfl_down(a1, 2, 8); a1 += __shfl_down(a1, 1, 8);
                if (seg == 0) redF[30 + j] = a1;
            }
        }
        __syncthreads();   // scores ready

        // ================= S2: softmaxes (wave-parallel) =================
        {
            const int wv = tid >> 6;
            if (wv == 0) {
                if (t <= 511) {
                    float sj = 0.f; int pres = 0;
                    if (tid < NBOX) { sj = redF[tid]; pres = (A.y[(size_t)t * 180 + tid * 6] != 0); }
                    softmax30_lane(tid, sj, pres, sm0);
                }
            } else if (wv == 1) {
                const int lane = tid - 64;
                if (t >= 1 && t <= 511) {
                    float sj = 0.f; int pres = 0;
                    if (lane < NBOX) { sj = redF[30 + lane]; pres = (A.y[(size_t)(t - 1) * 180 + lane * 6] != 0); }
                    softmax30_lane(lane, sj, pres, sm1);
                } else if (t == 0) {
                    if (lane < NBOX) sm1[lane] = 0.f;
                }
            } else if (wv == 2 && isCoord && t >= 1 && t <= 512) {
                const int lane = tid - 128;
                float* cscr = Wp + 960;
                float* csca = Wp + 992;
                const int u = t - 1;
                if (u == 0) { if (lane < NBOX) csca[lane] = 0.f; }
                else {
                    float sj = 0.f; int pres = 0;
                    if (lane < NBOX) { sj = cscr[lane]; pres = (A.y[(size_t)(u - 1) * 180 + lane * 6] != 0); }
                    softmax30_lane(lane, sj, pres, csca);
                }
            }
        }
        __syncthreads();   // sm0/sm1/csca ready

        // ================= S3: GEMVs + coord combine =================
        if (t <= 511 && tid < 240) {
            const int j = tid >> 3, q = tid & 7;
            if (q < 6) {
                const float* hrow = &Hs0[j * 516];
                const int saA = (q < 3) ? (2 * q) : (6 + 2 * (q - 3));
                float a0 = 0.f, a1 = 0.f;
                if (!isCoord) {
                    const float* wA = &Wp[saA * 516];
                    const float* wB = &Wp[(saA + 1) * 516];
#pragma unroll 4
                    for (int k = 0; k < 512; k += 4) {
                        const float4 h4 = ld4(hrow + k);
                        a0 += dot4(h4, ld4(wA + k));
                        a1 += dot4(h4, ld4(wB + k));
                    }
                } else {
                    const int slA = saA % 6, slB = slA + 1;
                    const float* mat = (saA < 6) ? A.Whh0 : A.Wih1;
                    const float* wA = mat + (size_t)((slA % 3) * 512 + 2 * w + ((slA >= 3) ? 1 : 0)) * 512;
                    const float* wB = mat + (size_t)((slB % 3) * 512 + 2 * w + ((slB >= 3) ? 1 : 0)) * 512;
#pragma unroll 4
                    for (int k = 0; k < 512; k += 4) {
                        const float4 h4 = ld4(hrow + k);
                        a0 += dot4(h4, ld4(wA + k));
                        a1 += dot4(h4, ld4(wB + k));
                    }
                }
                if (q < 3) { Z0s[j * 6 + 2 * q] = a0; Z0s[j * 6 + 2 * q + 1] = a1; }
                else { const int g = 2 * (q - 3); gi_s[j * 6 + g] = a0 + biA; gi_s[j * 6 + g + 1] = a1 + biB; }
            }
        }
        if (t >= 1 && t <= 511 && tid < 240) {
            const int j = tid >> 3, q = tid & 7;
            if (q < 3) {
                const float* hrow = &Hs1[j * 516];
                float a0 = 0.f, a1 = 0.f;
                if (!isCoord) {
                    const float* wA = &Wp[(12 + 2 * q) * 516];
                    const float* wB = &Wp[(13 + 2 * q) * 516];
#pragma unroll 4
                    for (int k = 0; k < 512; k += 4) {
                        const float4 h4 = ld4(hrow + k);
                        a0 += dot4(h4, ld4(wA + k));
                        a1 += dot4(h4, ld4(wB + k));
                    }
                } else {
                    const int slA = 2 * q, slB = slA + 1;
                    const float* wA = A.Whh1 + (size_t)((slA % 3) * 512 + 2 * w + ((slA >= 3) ? 1 : 0)) * 512;
                    const float* wB = A.Whh1 + (size_t)((slB % 3) * 512 + 2 * w + ((slB >= 3) ? 1 : 0)) * 512;
#pragma unroll 4
                    for (int k = 0; k < 512; k += 4) {
                        const float4 h4 = ld4(hrow + k);
                        a0 += dot4(h4, ld4(wA + k));
                        a1 += dot4(h4, ld4(wB + k));
                    }
                }
                Z1s[j * 6 + 2 * q] = a0; Z1s[j * 6 + 2 * q + 1] = a1;
            }
        }
        if (isCoord && t >= 1 && t <= 512) {
            const int u = t - 1;
            float* chc = Wp;
            float* csca = Wp + 992;
            const float* gp = A.gic + (size_t)u * 2880;
            float* hcout = A.hcg + (u & 1) * 960;
            if (tid < 960)       coord_comb_elem(chc, gp, A.bhhc, csca, hcout, tid, cz0);
            if (tid + 256 < 960) coord_comb_elem(chc, gp, A.bhhc, csca, hcout, tid + 256, cz1);
            if (tid + 512 < 960) coord_comb_elem(chc, gp, A.bhhc, csca, hcout, tid + 512, cz2);
            if (tid + 768 < 960) coord_comb_elem(chc, gp, A.bhhc, csca, hcout, tid + 768, cz3);
        }
        __syncthreads();   // Z0s/gi_s/Z1s/chc ready

        // ================= S5: combines + coord GEMV + classifier + finalize =================
        if (tid < 60 && t <= 511) {          // h1-combine(t)
            const float s = sm1[cjX];
            const float r = sigf(gi_s[cjX*6 + ciX*3 + 0] + s * Z1s[cjX*6 + ciX*3 + 0] + b1r);
            const float z = sigf(gi_s[cjX*6 + ciX*3 + 1] + s * Z1s[cjX*6 + ciX*3 + 1] + b1z);
            const float n = thf (gi_s[cjX*6 + ciX*3 + 2] + r * (s * Z1s[cjX*6 + ciX*3 + 2] + b1n));
            const float h1p = Hs1[cjX * 516 + cX];
            stg_c(A.h1g + (t % 3) * 15360 + cjX * 512 + cX, (1.f - z) * n + z * (s * h1p));
        }
        if (tid < 60 && t <= 510) {          // h0-combine(t+1)
            const float s = sm0[cjX];
            const float r = sigf(g_r + s * Z0s[cjX*6 + ciX*3 + 0] + b0r);
            const float z = sigf(g_z + s * Z0s[cjX*6 + ciX*3 + 1] + b0z);
            const float n = thf (g_n + r * (s * Z0s[cjX*6 + ciX*3 + 2] + b0n));
            const float h0p = Hs0[cjX * 516 + cX];
            stg_c(A.h0g + ((t + 1) & 1) * 15360 + cjX * 512 + cX, (1.f - z) * n + z * (s * h0p));
        }
        if (isCoord && t >= 1 && t <= 512) { // coord Zc GEMV + scores for next step
            float* chc = Wp;
            float* cscr = Wp + 960;
            if (tid < 960)       coord_gemv_elem(chc, A.Whhc, tid, cz0);
            if (tid + 256 < 960) coord_gemv_elem(chc, A.Whhc, tid + 256, cz1);
            if (tid + 512 < 960) coord_gemv_elem(chc, A.Whhc, tid + 512, cz2);
            if (tid + 768 < 960) coord_gemv_elem(chc, A.Whhc, tid + 768, cz3);
            if (tid < 240) {
                const int j = tid >> 3, seg = tid & 7;
                float p = 0.f;
#pragma unroll
                for (int c2 = seg * 4; c2 < seg * 4 + 4; ++c2) p += thf(chc[j * 32 + c2]) * A.wac[c2];
                p += __shfl_down(p, 4, 8); p += __shfl_down(p, 2, 8); p += __shfl_down(p, 1, 8);
                if (seg == 0) cscr[j] = p;
            }
        }
        if (!isCoord && t >= 2 && t <= 513 && tid < 240) {  // classifier unit w @ step t-2
            const int v = t - 2;
            const float* h1v = A.h1g + (v % 3) * 15360;
            const float* hcv = A.hcg + (v & 1) * 960;
            const int j = tid >> 3, seg = tid & 7;
            {
                const float* w1r = A.W1T + (size_t)w * 544 + seg * 64;
                const float* hp = h1v + j * 512 + seg * 64;
                float acc = 0.f;
#pragma unroll
                for (int i = 0; i < 32; ++i) {
                    const float2 hv = ldg_c2(hp + 2 * i);
                    acc += hv.x * w1r[2 * i] + hv.y * w1r[2 * i + 1];
                }
                if (seg == 7) {
                    const float* w1h = A.W1T + (size_t)w * 544 + 512;
#pragma unroll
                    for (int i = 0; i < 16; ++i) {
                        const float2 hv = ldg_c2(hcv + j * 32 + 2 * i);
                        acc += hv.x * w1h[2 * i] + hv.y * w1h[2 * i + 1];
                    }
                }
                acc += __shfl_down(acc, 4, 8); acc += __shfl_down(acc, 2, 8); acc += __shfl_down(acc, 1, 8);
                if (seg == 0) {
                    const float uu = fmaxf(clb + acc, 0.f);
                    stg_c2(A.partials + (t & 1) * 16384 + w * 64 + j * 2, uu * c20, uu * c21);
                }
            }
            if (w == 254) {  // also unit 255
                const float* w1r = A.W1T + (size_t)255 * 544 + seg * 64;
                const float* hp = h1v + j * 512 + seg * 64;
                float acc = 0.f;
#pragma unroll
                for (int i = 0; i < 32; ++i) {
                    const float2 hv = ldg_c2(hp + 2 * i);
                    acc += hv.x * w1r[2 * i] + hv.y * w1r[2 * i + 1];
                }
                if (seg == 7) {
                    const float* w1h = A.W1T + (size_t)255 * 544 + 512;
#pragma unroll
                    for (int i = 0; i < 16; ++i) {
                        const float2 hv = ldg_c2(hcv + j * 32 + 2 * i);
                        acc += hv.x * w1h[2 * i] + hv.y * w1h[2 * i + 1];
                    }
                }
                acc += __shfl_down(acc, 4, 8); acc += __shfl_down(acc, 2, 8); acc += __shfl_down(acc, 1, 8);
                if (seg == 0) {
                    const float uu = fmaxf(clb2 + acc, 0.f);
                    stg_c2(A.partials + (t & 1) * 16384 + 255 * 64 + j * 2, uu * c202, uu * c212);
                }
            }
        }
        if (w < 30 && t >= 3) {              // finalize step t-3 (track j = w): partial sums
            const float* pp = A.partials + ((t - 1) & 1) * 16384;
            const float2 v2 = ldg_c2(pp + tid * 64 + w * 2);
            float q0 = v2.x, q1 = v2.y;
            for (int off = 32; off; off >>= 1) { q0 += __shfl_down(q0, off); q1 += __shfl_down(q1, off); }
            if ((tid & 63) == 0) { redF[60 + (tid >> 6) * 2] = q0; redF[61 + (tid >> 6) * 2] = q1; }
        }
        __syncthreads();
        if (w < 30 && t >= 3 && tid == 0) {
            const int f = t - 3;
            float o0 = A.b2[0] + redF[60] + redF[62] + redF[64] + redF[66];
            float o1 = A.b2[1] + redF[61] + redF[63] + redF[65] + redF[67];
            const int* yb = A.y + (size_t)f * 180 + w * 6;
            const float pm = (yb[0] != 0) ? 1.f : 0.f;
            const float m = fmaxf(o0, o1);
            const float lse = m + __logf(__expf(o0 - m) + __expf(o1 - m));
            const float lt = (yb[5] == 0) ? o0 : o1;
            lossSum += pm * (lse - lt);
            A.out[1 + (size_t)f * 60 + w * 2]     = o0 * pm;
            A.out[1 + (size_t)f * 60 + w * 2 + 1] = o1 * pm;
        }
        gbar(A.bar, ++ep, w);
    }

    // ---- total loss ----
    if (w < 30 && tid == 0) stg_c(A.lossbuf + w, lossSum);
    gbar(A.bar, ++ep, w);
    if (w == 0 && tid == 0) {
        float s = 0.f;
        for (int j = 0; j < NBOX; ++j) s += ldg_c(A.lossbuf + j);
        A.out[0] = s;
    }
}

// ---------------------------------------------------------------------------
extern "C" void kernel_launch(void* const* d_in, const int* in_sizes, int n_in,
                              void* d_out, int out_size, void* d_ws, size_t ws_size,
                              hipStream_t stream) {
    (void)in_sizes; (void)n_in; (void)out_size; (void)ws_size;
    const int*   y     = (const int*)d_in[1];
    const float* flow  = (const float*)d_in[2];
    const float* W_phi = (const float*)d_in[3];
    const float* b_phi = (const float*)d_in[4];
    const float* Wih0  = (const float*)d_in[5];
    const float* Whh0  = (const float*)d_in[6];
    const float* bih0  = (const float*)d_in[7];
    const float* bhh0  = (const float*)d_in[8];
    const float* Wih1  = (const float*)d_in[9];
    const float* Whh1  = (const float*)d_in[10];
    const float* bih1  = (const float*)d_in[11];
    const float* bhh1  = (const float*)d_in[12];
    const float* Wihc  = (const float*)d_in[13];
    const float* Whhc  = (const float*)d_in[14];
    const float* bihc  = (const float*)d_in[15];
    const float* bhhc  = (const float*)d_in[16];
    const float* W1    = (const float*)d_in[17];
    const float* b1    = (const float*)d_in[18];
    const float* W2    = (const float*)d_in[19];
    const float* b2    = (const float*)d_in[20];
    const float* wa    = (const float*)d_in[21];
    const float* wac   = (const float*)d_in[22];
    float* out = (float*)d_out;

    float* ws = (float*)d_ws;
    float* xv   = ws;  ws += (size_t)M1 * N1;
    float* gi0  = ws;  ws += (size_t)M2 * N2;
    float* gic  = ws;  ws += (size_t)M2 * 96;
    float* W1T  = ws;  ws += 544 * 256;
    float* h0g  = ws;  ws += 2 * NBOX * 512;
    float* h1g  = ws;  ws += 3 * NBOX * 512;
    float* hcg  = ws;  ws += 2 * NBOX * 32;
    float* partials = ws; ws += 2 * 256 * 64;
    float* lossbuf  = ws; ws += 32;
    unsigned* barmem = (unsigned*)ws; ws += 1088;

    (void)hipFuncSetAttribute((const void*)persist,
                              hipFuncAttributeMaxDynamicSharedMemorySize, DYN_BYTES);

    hipLaunchKernelGGL(init_k, dim3(1), dim3(256), 0, stream, barmem);
    hipLaunchKernelGGL(gemm_phi, dim3(M1 / 64, N1 / 64), dim3(256), 0, stream, flow, W_phi, b_phi, xv);
    hipLaunchKernelGGL(gemm_gi0, dim3(M2 / 64, N2 / 64), dim3(256), 0, stream, xv, Wih0, bih0, gi0);
    hipLaunchKernelGGL(gic_kernel, dim3((M2 * 96 + 255) / 256), dim3(256), 0, stream, y, Wihc, bihc, gic);
    hipLaunchKernelGGL(transpose_w1, dim3((544 * 256 + 255) / 256), dim3(256), 0, stream, W1, W1T);

    PArgs A;
    A.gi0 = gi0; A.gic = gic;
    A.Whh0 = Whh0; A.Wih1 = Wih1; A.Whh1 = Whh1; A.Whhc = Whhc;
    A.bhh0 = bhh0; A.bih1 = bih1; A.bhh1 = bhh1; A.bhhc = bhhc;
    A.W1T = W1T; A.b1 = b1; A.W2 = W2; A.b2 = b2; A.wa = wa; A.wac = wac;
    A.y = y;
    A.h0g = h0g; A.h1g = h1g; A.hcg = hcg;
    A.partials = partials; A.lossbuf = lossbuf; A.out = out;
    A.bar = barmem;
    hipLaunchKernelGGL(persist, dim3(NWG), dim3(256), DYN_BYTES, stream, A);
}